// Round 4
// baseline (167.427 us; speedup 1.0000x reference)
//
#include <hip/hip_runtime.h>

#define WIRES 14
#define NSTATE (1 << WIRES)   // 16384
#define NTH 1024
#define NVB 13                // variational blocks
#define F_OFF (NVB * 16)      // float2 offset of per-sample fused-ENC region in ws

__device__ __forceinline__ float2 cmul(float2 a, float2 b) {
    return make_float2(a.x * b.x - a.y * b.y, a.x * b.y + a.y * b.x);
}

// ============ kernel 1: fuse each 10-gate variational block into one 4x4 ============
__global__ void gate_prep(const float* __restrict__ params, float2* __restrict__ G) {
    int k = threadIdx.x;
    if (k >= NVB) return;
    const float* p = params + k * 10;

    float2 U1[4], U2[4], U3[4], U4[4];
    auto rzrx = [](float trx, float trz, float2* U) {
        float cx, sx, cz, sz;
        sincosf(trx * 0.5f, &sx, &cx);
        sincosf(trz * 0.5f, &sz, &cz);
        float2 e0 = make_float2(cz, -sz);   // e^{-i h}
        float2 e1 = make_float2(cz,  sz);   // e^{+i h}
        U[0] = cmul(e0, make_float2(cx, 0.f));
        U[1] = cmul(e0, make_float2(0.f, -sx));
        U[2] = cmul(e1, make_float2(0.f, -sx));
        U[3] = cmul(e1, make_float2(cx, 0.f));
    };
    rzrx(p[0], p[1], U1);   // q1, first
    rzrx(p[2], p[3], U2);   // q2, first
    rzrx(p[5], p[6], U3);   // q1, second
    rzrx(p[7], p[8], U4);   // q2, second

    float2 K12[16], K34[16];
    for (int r1 = 0; r1 < 2; ++r1)
        for (int r2 = 0; r2 < 2; ++r2)
            for (int c1 = 0; c1 < 2; ++c1)
                for (int c2 = 0; c2 < 2; ++c2) {
                    int idx = (r1 * 2 + r2) * 4 + (c1 * 2 + c2);
                    K12[idx] = cmul(U1[r1 * 2 + c1], U2[r2 * 2 + c2]);
                    K34[idx] = cmul(U3[r1 * 2 + c1], U4[r2 * 2 + c2]);
                }

    float2 C1[16], C2[16];
    for (int i = 0; i < 16; ++i) { C1[i] = make_float2(0.f, 0.f); C2[i] = make_float2(0.f, 0.f); }
    {
        float c, s;
        sincosf(p[4] * 0.5f, &s, &c);        // CRY ctrl=q1(high local bit), tgt=q2
        C1[0]  = make_float2(1.f, 0.f); C1[5]  = make_float2(1.f, 0.f);
        C1[10] = make_float2(c, 0.f);   C1[11] = make_float2(-s, 0.f);
        C1[14] = make_float2(s, 0.f);   C1[15] = make_float2(c, 0.f);
        sincosf(p[9] * 0.5f, &s, &c);        // CRY ctrl=q2(low local bit), tgt=q1
        C2[0]  = make_float2(1.f, 0.f); C2[10] = make_float2(1.f, 0.f);
        C2[5]  = make_float2(c, 0.f);   C2[7]  = make_float2(-s, 0.f);
        C2[13] = make_float2(s, 0.f);   C2[15] = make_float2(c, 0.f);
    }

    float2 T1[16], T2[16], Gk[16];
    for (int r = 0; r < 4; ++r)
        for (int c = 0; c < 4; ++c) {
            float2 a = make_float2(0.f, 0.f);
            for (int j = 0; j < 4; ++j) { float2 m = cmul(C1[r*4+j], K12[j*4+c]); a.x += m.x; a.y += m.y; }
            T1[r*4+c] = a;
        }
    for (int r = 0; r < 4; ++r)
        for (int c = 0; c < 4; ++c) {
            float2 a = make_float2(0.f, 0.f);
            for (int j = 0; j < 4; ++j) { float2 m = cmul(K34[r*4+j], T1[j*4+c]); a.x += m.x; a.y += m.y; }
            T2[r*4+c] = a;
        }
    for (int r = 0; r < 4; ++r)
        for (int c = 0; c < 4; ++c) {
            float2 a = make_float2(0.f, 0.f);
            for (int j = 0; j < 4; ++j) { float2 m = cmul(C2[r*4+j], T2[j*4+c]); a.x += m.x; a.y += m.y; }
            Gk[r*4+c] = a;
        }
    for (int i = 0; i < 16; ++i) G[k * 16 + i] = Gk[i];
}

// ============ kernel 1b: per-sample fuse ENC pair j into layer-1 block: F = G_j * E ============
__global__ void enc_prep(const float* __restrict__ inputs, float2* __restrict__ ws, int batch) {
    int idx = blockIdx.x * blockDim.x + threadIdx.x;
    if (idx >= batch * 7) return;
    const int b = idx / 7, j = idx % 7;
    float c1, s1, c2, s2;
    sincosf(inputs[b * WIRES + 2*j]     * 0.5f, &s1, &c1);
    sincosf(inputs[b * WIRES + 2*j + 1] * 0.5f, &s2, &c2);
    float E[16] = { c1*c2, -c1*s2, -s1*c2,  s1*s2,
                    c1*s2,  c1*c2, -s1*s2, -s1*c2,
                    s1*c2, -s1*s2,  c1*c2, -c1*s2,
                    s1*s2,  s1*c2,  c1*s2,  c1*c2 };
    const float2* Gj = ws + j * 16;
    float2* F = ws + F_OFF + (size_t)(b * 7 + j) * 16;
    #pragma unroll
    for (int r = 0; r < 4; ++r)
        #pragma unroll
        for (int c = 0; c < 4; ++c) {
            float2 a = make_float2(0.f, 0.f);
            #pragma unroll
            for (int k = 0; k < 4; ++k) {
                a.x += Gj[r*4+k].x * E[k*4+c];
                a.y += Gj[r*4+k].y * E[k*4+c];
            }
            F[r*4+c] = a;
        }
}

// ============ sim kernel helpers ============

// GF(2)-linear LDS swizzle on float2 index
__device__ __forceinline__ int swz(int i) { return i ^ ((i >> 4) & 15); }

// compile-time: scatter r's 4 bits to global bit positions, then swizzle
template<int B3,int B2,int B1,int B0>
constexpr int prc(int r) {
    int s = ((r&1)?(1<<B0):0) | ((r&2)?(1<<B1):0) | ((r&4)?(1<<B2):0) | ((r&8)?(1<<B3):0);
    return s ^ ((s >> 4) & 15);
}

// apply complex 4x4 gate on local register-bit pair (PH=high, PL=low).
// g is a WAVE-UNIFORM global pointer -> compiler scalarizes loads into SGPRs,
// so gate coefficients cost zero VGPRs.
template<int PH,int PL>
__device__ __forceinline__ void gate4(float2 v[16], const float2* __restrict__ g) {
    constexpr int mask = (1<<PH) | (1<<PL);
    #pragma unroll
    for (int base = 0; base < 16; ++base) {
        if (base & mask) continue;
        const int i0 = base, i1 = base | (1<<PL), i2 = base | (1<<PH), i3 = base | mask;
        float2 v0 = v[i0], v1 = v[i1], v2 = v[i2], v3 = v[i3];
        float2 w0, w1, w2, w3;
#define CROW(R, W)                                                                     \
        W.x = g[4*R+0].x*v0.x - g[4*R+0].y*v0.y + g[4*R+1].x*v1.x - g[4*R+1].y*v1.y    \
            + g[4*R+2].x*v2.x - g[4*R+2].y*v2.y + g[4*R+3].x*v3.x - g[4*R+3].y*v3.y;   \
        W.y = g[4*R+0].x*v0.y + g[4*R+0].y*v0.x + g[4*R+1].x*v1.y + g[4*R+1].y*v1.x    \
            + g[4*R+2].x*v2.y + g[4*R+2].y*v2.x + g[4*R+3].x*v3.y + g[4*R+3].y*v3.x;
        CROW(0, w0) CROW(1, w1) CROW(2, w2) CROW(3, w3)
#undef CROW
        v[i0] = w0; v[i1] = w1; v[i2] = w2; v[i3] = w3;
    }
}

// ============ kernel 2: full per-sample simulation, register-blocked ============
// LDS (128 KiB) caps residency at 1 block/CU = 4 waves/EU; pin the register
// allocator to exactly that so the VGPR budget is 128 (kills scratch spill).
__global__ __launch_bounds__(NTH, 4) __attribute__((amdgpu_waves_per_eu(4, 4)))
void sim(const float2* __restrict__ ws, float* __restrict__ out) {
    __shared__ float2 st[NSTATE];      // 128 KiB state
    const int b = blockIdx.x;
    const int t = threadIdx.x;
    const float2* G = ws;                                 // 13 fused variational 4x4
    const float2* F = ws + F_OFF + (size_t)b * 7 * 16;    // 7 per-sample ENC-fused 4x4

    float2 v[16];

    // ---- P1: register bits {13,12,11,10}; state = |0..0> directly ----
    {
        #pragma unroll
        for (int r = 0; r < 16; ++r) v[r] = make_float2(0.f, 0.f);
        if (t == 0) v[0].x = 1.f;
        gate4<3,2>(v, F + 0*16);    // ENC0*G0 on (13,12)
        gate4<1,0>(v, F + 1*16);    // ENC1*G1 on (11,10)
        gate4<2,1>(v, G + 7*16);    // G7 on (12,11)
        const int pb = swz(t);                         // tb = t (bits 9..0)
        #pragma unroll
        for (int r = 0; r < 16; ++r) st[pb ^ prc<13,12,11,10>(r)] = v[r];
    }
    __syncthreads();

    // ---- P2: register bits {9,8,7,6} ----
    {
        const int tb = (t & 63) | ((t & 0x3C0) << 4);
        const int pb = swz(tb);
        #pragma unroll
        for (int r = 0; r < 16; ++r) v[r] = st[pb ^ prc<9,8,7,6>(r)];
        gate4<3,2>(v, F + 2*16);    // ENC2*G2 on (9,8)
        gate4<1,0>(v, F + 3*16);    // ENC3*G3 on (7,6)
        gate4<2,1>(v, G + 9*16);    // G9 on (8,7)
        #pragma unroll
        for (int r = 0; r < 16; ++r) st[pb ^ prc<9,8,7,6>(r)] = v[r];
    }
    __syncthreads();

    // ---- P3: register bits {5,4,3,2} ----
    {
        const int tb = (t & 3) | ((t & 0x3FC) << 4);
        const int pb = swz(tb);
        #pragma unroll
        for (int r = 0; r < 16; ++r) v[r] = st[pb ^ prc<5,4,3,2>(r)];
        gate4<3,2>(v, F + 4*16);    // ENC4*G4 on (5,4)
        gate4<1,0>(v, F + 5*16);    // ENC5*G5 on (3,2)
        gate4<2,1>(v, G + 11*16);   // G11 on (4,3)
        #pragma unroll
        for (int r = 0; r < 16; ++r) st[pb ^ prc<5,4,3,2>(r)] = v[r];
    }
    __syncthreads();

    // ---- P4: register bits {3,2,1,0} ----
    {
        const int tb = t << 4;
        const int pb = swz(tb);
        #pragma unroll
        for (int r = 0; r < 16; ++r) v[r] = st[pb ^ prc<3,2,1,0>(r)];
        gate4<1,0>(v, F + 6*16);    // ENC6*G6 on (1,0)
        gate4<2,1>(v, G + 12*16);   // G12 on (2,1)
        #pragma unroll
        for (int r = 0; r < 16; ++r) st[pb ^ prc<3,2,1,0>(r)] = v[r];
    }
    __syncthreads();

    // ---- P5: register bits {10,9,6,5}; reduce directly from registers ----
    int tb5;
    {
        tb5 = (t & 31) | ((t & 0x60) << 2) | ((t & 0x380) << 4);
        const int pb = swz(tb5);
        #pragma unroll
        for (int r = 0; r < 16; ++r) v[r] = st[pb ^ prc<10,9,6,5>(r)];
        gate4<3,2>(v, G + 8*16);    // G8 on (10,9)
        gate4<1,0>(v, G + 10*16);   // G10 on (6,5)
    }

    // ---- <Z>: per-thread partials from registers ----
    float pr[16], S = 0.f;
    #pragma unroll
    for (int r = 0; r < 16; ++r) { pr[r] = v[r].x * v[r].x + v[r].y * v[r].y; S += pr[r]; }
    float s5 = 0.f, s6 = 0.f, s9 = 0.f, s10 = 0.f;   // sums where that R-bit is 1
    #pragma unroll
    for (int r = 0; r < 16; ++r) {
        if (r & 1) s5  += pr[r];
        if (r & 2) s6  += pr[r];
        if (r & 4) s9  += pr[r];
        if (r & 8) s10 += pr[r];
    }
    float zq[WIRES];
    #pragma unroll
    for (int q = 0; q < WIRES; ++q) {
        const int bb = 13 - q;
        if      (bb == 10) zq[q] = S - 2.f * s10;
        else if (bb == 9)  zq[q] = S - 2.f * s9;
        else if (bb == 6)  zq[q] = S - 2.f * s6;
        else if (bb == 5)  zq[q] = S - 2.f * s5;
        else               zq[q] = ((tb5 >> bb) & 1) ? -S : S;
    }
    #pragma unroll
    for (int q = 0; q < WIRES; ++q) {
        #pragma unroll
        for (int off = 32; off >= 1; off >>= 1)
            zq[q] += __shfl_xor(zq[q], off, 64);
    }
    __syncthreads();                    // all P5 state reads done; reuse st as scratch
    float* part = (float*)st;
    const int lane = t & 63, wv = t >> 6;
    if (lane == 0) {
        #pragma unroll
        for (int q = 0; q < WIRES; ++q) part[wv * WIRES + q] = zq[q];
    }
    __syncthreads();
    if (t < WIRES) {
        float s = 0.f;
        #pragma unroll
        for (int w = 0; w < NTH / 64; ++w) s += part[w * WIRES + t];
        out[b * WIRES + t] = s;
    }
}

// ============ fallback (ws too small): R2 kernel, ENC fused in-block via LDS ============
__global__ __launch_bounds__(NTH) void sim_fb(const float* __restrict__ inputs,
                                              const float2* __restrict__ gates,
                                              float* __restrict__ out) {
    __shared__ float2 st[NSTATE];
    __shared__ float2 Fsh[7 * 16];
    const int b = blockIdx.x;
    const int t = threadIdx.x;
    const float* inp = inputs + b * WIRES;

    if (t < 7) {
        const int j = t;
        float c1, s1, c2, s2;
        sincosf(inp[2*j]     * 0.5f, &s1, &c1);
        sincosf(inp[2*j + 1] * 0.5f, &s2, &c2);
        float E[16] = { c1*c2, -c1*s2, -s1*c2,  s1*s2,
                        c1*s2,  c1*c2, -s1*s2, -s1*c2,
                        s1*c2, -s1*s2,  c1*c2, -c1*s2,
                        s1*s2,  s1*c2,  c1*s2,  c1*c2 };
        const float2* Gj = gates + j * 16;
        #pragma unroll
        for (int r = 0; r < 4; ++r)
            #pragma unroll
            for (int c = 0; c < 4; ++c) {
                float2 a = make_float2(0.f, 0.f);
                #pragma unroll
                for (int k = 0; k < 4; ++k) {
                    a.x += Gj[r*4+k].x * E[k*4+c];
                    a.y += Gj[r*4+k].y * E[k*4+c];
                }
                Fsh[j*16 + r*4 + c] = a;
            }
    }
    __syncthreads();

    float2 v[16];
    {
        #pragma unroll
        for (int r = 0; r < 16; ++r) v[r] = make_float2(0.f, 0.f);
        if (t == 0) v[0].x = 1.f;
        gate4<3,2>(v, Fsh + 0*16);
        gate4<1,0>(v, Fsh + 1*16);
        gate4<2,1>(v, gates + 7*16);
        const int pb = swz(t);
        #pragma unroll
        for (int r = 0; r < 16; ++r) st[pb ^ prc<13,12,11,10>(r)] = v[r];
    }
    __syncthreads();
    {
        const int tb = (t & 63) | ((t & 0x3C0) << 4);
        const int pb = swz(tb);
        #pragma unroll
        for (int r = 0; r < 16; ++r) v[r] = st[pb ^ prc<9,8,7,6>(r)];
        gate4<3,2>(v, Fsh + 2*16);
        gate4<1,0>(v, Fsh + 3*16);
        gate4<2,1>(v, gates + 9*16);
        #pragma unroll
        for (int r = 0; r < 16; ++r) st[pb ^ prc<9,8,7,6>(r)] = v[r];
    }
    __syncthreads();
    {
        const int tb = (t & 3) | ((t & 0x3FC) << 4);
        const int pb = swz(tb);
        #pragma unroll
        for (int r = 0; r < 16; ++r) v[r] = st[pb ^ prc<5,4,3,2>(r)];
        gate4<3,2>(v, Fsh + 4*16);
        gate4<1,0>(v, Fsh + 5*16);
        gate4<2,1>(v, gates + 11*16);
        #pragma unroll
        for (int r = 0; r < 16; ++r) st[pb ^ prc<5,4,3,2>(r)] = v[r];
    }
    __syncthreads();
    {
        const int tb = t << 4;
        const int pb = swz(tb);
        #pragma unroll
        for (int r = 0; r < 16; ++r) v[r] = st[pb ^ prc<3,2,1,0>(r)];
        gate4<1,0>(v, Fsh + 6*16);
        gate4<2,1>(v, gates + 12*16);
        #pragma unroll
        for (int r = 0; r < 16; ++r) st[pb ^ prc<3,2,1,0>(r)] = v[r];
    }
    __syncthreads();
    int tb5;
    {
        tb5 = (t & 31) | ((t & 0x60) << 2) | ((t & 0x380) << 4);
        const int pb = swz(tb5);
        #pragma unroll
        for (int r = 0; r < 16; ++r) v[r] = st[pb ^ prc<10,9,6,5>(r)];
        gate4<3,2>(v, gates + 8*16);
        gate4<1,0>(v, gates + 10*16);
    }
    float pr[16], S = 0.f;
    #pragma unroll
    for (int r = 0; r < 16; ++r) { pr[r] = v[r].x * v[r].x + v[r].y * v[r].y; S += pr[r]; }
    float s5 = 0.f, s6 = 0.f, s9 = 0.f, s10 = 0.f;
    #pragma unroll
    for (int r = 0; r < 16; ++r) {
        if (r & 1) s5  += pr[r];
        if (r & 2) s6  += pr[r];
        if (r & 4) s9  += pr[r];
        if (r & 8) s10 += pr[r];
    }
    float zq[WIRES];
    #pragma unroll
    for (int q = 0; q < WIRES; ++q) {
        const int bb = 13 - q;
        if      (bb == 10) zq[q] = S - 2.f * s10;
        else if (bb == 9)  zq[q] = S - 2.f * s9;
        else if (bb == 6)  zq[q] = S - 2.f * s6;
        else if (bb == 5)  zq[q] = S - 2.f * s5;
        else               zq[q] = ((tb5 >> bb) & 1) ? -S : S;
    }
    #pragma unroll
    for (int q = 0; q < WIRES; ++q) {
        #pragma unroll
        for (int off = 32; off >= 1; off >>= 1)
            zq[q] += __shfl_xor(zq[q], off, 64);
    }
    __syncthreads();
    float* part = (float*)Fsh;
    const int lane = t & 63, wv = t >> 6;
    if (lane == 0) {
        #pragma unroll
        for (int q = 0; q < WIRES; ++q) part[wv * WIRES + q] = zq[q];
    }
    __syncthreads();
    if (t < WIRES) {
        float s = 0.f;
        #pragma unroll
        for (int w = 0; w < NTH / 64; ++w) s += part[w * WIRES + t];
        out[b * WIRES + t] = s;
    }
}

extern "C" void kernel_launch(void* const* d_in, const int* in_sizes, int n_in,
                              void* d_out, int out_size, void* d_ws, size_t ws_size,
                              hipStream_t stream) {
    const float* inputs = (const float*)d_in[0];
    const float* params = (const float*)d_in[1];
    float* out = (float*)d_out;
    float2* ws = (float2*)d_ws;

    const int batch = in_sizes[0] / WIRES;
    const size_t needed = (F_OFF + (size_t)batch * 7 * 16) * sizeof(float2);

    gate_prep<<<1, 64, 0, stream>>>(params, ws);
    if (ws_size >= needed) {
        enc_prep<<<(batch * 7 + 255) / 256, 256, 0, stream>>>(inputs, ws, batch);
        sim<<<batch, NTH, 0, stream>>>(ws, out);
    } else {
        sim_fb<<<batch, NTH, 0, stream>>>(inputs, ws, out);
    }
}

// Round 5
// 163.247 us; speedup vs baseline: 1.0256x; 1.0256x over previous
//
#include <hip/hip_runtime.h>

#define WIRES 14
#define NSTATE (1 << WIRES)   // 16384
#define NTH 1024
#define NVB 13                // variational blocks
#define F_OFF (NVB * 16)      // float2 offset of per-sample fused-ENC region in ws

typedef __attribute__((ext_vector_type(16))) float f16v;

__device__ __forceinline__ float2 cmul(float2 a, float2 b) {
    return make_float2(a.x * b.x - a.y * b.y, a.x * b.y + a.y * b.x);
}

// ============ kernel 1: fuse each 10-gate variational block into one 4x4 ============
__global__ void gate_prep(const float* __restrict__ params, float2* __restrict__ G) {
    int k = threadIdx.x;
    if (k >= NVB) return;
    const float* p = params + k * 10;

    float2 U1[4], U2[4], U3[4], U4[4];
    auto rzrx = [](float trx, float trz, float2* U) {
        float cx, sx, cz, sz;
        sincosf(trx * 0.5f, &sx, &cx);
        sincosf(trz * 0.5f, &sz, &cz);
        float2 e0 = make_float2(cz, -sz);   // e^{-i h}
        float2 e1 = make_float2(cz,  sz);   // e^{+i h}
        U[0] = cmul(e0, make_float2(cx, 0.f));
        U[1] = cmul(e0, make_float2(0.f, -sx));
        U[2] = cmul(e1, make_float2(0.f, -sx));
        U[3] = cmul(e1, make_float2(cx, 0.f));
    };
    rzrx(p[0], p[1], U1);   // q1, first
    rzrx(p[2], p[3], U2);   // q2, first
    rzrx(p[5], p[6], U3);   // q1, second
    rzrx(p[7], p[8], U4);   // q2, second

    float2 K12[16], K34[16];
    for (int r1 = 0; r1 < 2; ++r1)
        for (int r2 = 0; r2 < 2; ++r2)
            for (int c1 = 0; c1 < 2; ++c1)
                for (int c2 = 0; c2 < 2; ++c2) {
                    int idx = (r1 * 2 + r2) * 4 + (c1 * 2 + c2);
                    K12[idx] = cmul(U1[r1 * 2 + c1], U2[r2 * 2 + c2]);
                    K34[idx] = cmul(U3[r1 * 2 + c1], U4[r2 * 2 + c2]);
                }

    float2 C1[16], C2[16];
    for (int i = 0; i < 16; ++i) { C1[i] = make_float2(0.f, 0.f); C2[i] = make_float2(0.f, 0.f); }
    {
        float c, s;
        sincosf(p[4] * 0.5f, &s, &c);        // CRY ctrl=q1(high local bit), tgt=q2
        C1[0]  = make_float2(1.f, 0.f); C1[5]  = make_float2(1.f, 0.f);
        C1[10] = make_float2(c, 0.f);   C1[11] = make_float2(-s, 0.f);
        C1[14] = make_float2(s, 0.f);   C1[15] = make_float2(c, 0.f);
        sincosf(p[9] * 0.5f, &s, &c);        // CRY ctrl=q2(low local bit), tgt=q1
        C2[0]  = make_float2(1.f, 0.f); C2[10] = make_float2(1.f, 0.f);
        C2[5]  = make_float2(c, 0.f);   C2[7]  = make_float2(-s, 0.f);
        C2[13] = make_float2(s, 0.f);   C2[15] = make_float2(c, 0.f);
    }

    float2 T1[16], T2[16], Gk[16];
    for (int r = 0; r < 4; ++r)
        for (int c = 0; c < 4; ++c) {
            float2 a = make_float2(0.f, 0.f);
            for (int j = 0; j < 4; ++j) { float2 m = cmul(C1[r*4+j], K12[j*4+c]); a.x += m.x; a.y += m.y; }
            T1[r*4+c] = a;
        }
    for (int r = 0; r < 4; ++r)
        for (int c = 0; c < 4; ++c) {
            float2 a = make_float2(0.f, 0.f);
            for (int j = 0; j < 4; ++j) { float2 m = cmul(K34[r*4+j], T1[j*4+c]); a.x += m.x; a.y += m.y; }
            T2[r*4+c] = a;
        }
    for (int r = 0; r < 4; ++r)
        for (int c = 0; c < 4; ++c) {
            float2 a = make_float2(0.f, 0.f);
            for (int j = 0; j < 4; ++j) { float2 m = cmul(C2[r*4+j], T2[j*4+c]); a.x += m.x; a.y += m.y; }
            Gk[r*4+c] = a;
        }
    for (int i = 0; i < 16; ++i) G[k * 16 + i] = Gk[i];
}

// ============ kernel 1b: per-sample fuse ENC pair j into layer-1 block: F = G_j * E ============
__global__ void enc_prep(const float* __restrict__ inputs, float2* __restrict__ ws, int batch) {
    int idx = blockIdx.x * blockDim.x + threadIdx.x;
    if (idx >= batch * 7) return;
    const int b = idx / 7, j = idx % 7;
    float c1, s1, c2, s2;
    sincosf(inputs[b * WIRES + 2*j]     * 0.5f, &s1, &c1);
    sincosf(inputs[b * WIRES + 2*j + 1] * 0.5f, &s2, &c2);
    float E[16] = { c1*c2, -c1*s2, -s1*c2,  s1*s2,
                    c1*s2,  c1*c2, -s1*s2, -s1*c2,
                    s1*c2, -s1*s2,  c1*c2, -c1*s2,
                    s1*s2,  s1*c2,  c1*s2,  c1*c2 };
    const float2* Gj = ws + j * 16;
    float2* F = ws + F_OFF + (size_t)(b * 7 + j) * 16;
    #pragma unroll
    for (int r = 0; r < 4; ++r)
        #pragma unroll
        for (int c = 0; c < 4; ++c) {
            float2 a = make_float2(0.f, 0.f);
            #pragma unroll
            for (int k = 0; k < 4; ++k) {
                a.x += Gj[r*4+k].x * E[k*4+c];
                a.y += Gj[r*4+k].y * E[k*4+c];
            }
            F[r*4+c] = a;
        }
}

// ============ sim kernel helpers ============

// GF(2)-linear LDS swizzle on float2 index
__device__ __forceinline__ int swz(int i) { return i ^ ((i >> 4) & 15); }

// compile-time: scatter r's 4 bits to global bit positions, then swizzle
template<int B3,int B2,int B1,int B0>
constexpr int prc(int r) {
    int s = ((r&1)?(1<<B0):0) | ((r&2)?(1<<B1):0) | ((r&4)?(1<<B2):0) | ((r&8)?(1<<B3):0);
    return s ^ ((s >> 4) & 15);
}

// scalar-load 32 floats (one 4x4 complex gate) from a wave-uniform global
// address into SGPRs: zero VGPR cost for gate coefficients.
__device__ __forceinline__ void sload32(const float2* p, f16v& lo, f16v& hi) {
    asm volatile("s_load_dwordx16 %0, %2, 0x0\n\t"
                 "s_load_dwordx16 %1, %2, 0x40\n\t"
                 "s_waitcnt lgkmcnt(0)"
                 : "=&s"(lo), "=&s"(hi)
                 : "s"(p));
}

// complex 4x4 gate on local register-bit pair (PH=high, PL=low), coeffs in SGPRs.
// Row R, col c coefficient: flat float index 8R+2c(+1) -> rows 0,1 in lo, rows 2,3 in hi.
template<int PH,int PL>
__device__ __forceinline__ void gate4s(float2 v[16], const float2* __restrict__ gp) {
    f16v lo, hi;
    sload32(gp, lo, hi);
    constexpr int mask = (1<<PH) | (1<<PL);
    #pragma unroll
    for (int base = 0; base < 16; ++base) {
        if (base & mask) continue;
        const int i0 = base, i1 = base | (1<<PL), i2 = base | (1<<PH), i3 = base | mask;
        float2 v0 = v[i0], v1 = v[i1], v2 = v[i2], v3 = v[i3];
        float2 w0, w1, w2, w3;
#define CROW(V, O, W)                                                     \
        W.x = V[(O)+0]*v0.x - V[(O)+1]*v0.y + V[(O)+2]*v1.x - V[(O)+3]*v1.y \
            + V[(O)+4]*v2.x - V[(O)+5]*v2.y + V[(O)+6]*v3.x - V[(O)+7]*v3.y; \
        W.y = V[(O)+0]*v0.y + V[(O)+1]*v0.x + V[(O)+2]*v1.y + V[(O)+3]*v1.x \
            + V[(O)+4]*v2.y + V[(O)+5]*v2.x + V[(O)+6]*v3.y + V[(O)+7]*v3.x;
        CROW(lo, 0, w0) CROW(lo, 8, w1) CROW(hi, 0, w2) CROW(hi, 8, w3)
#undef CROW
        v[i0] = w0; v[i1] = w1; v[i2] = w2; v[i3] = w3;
    }
}

// plain-VGPR variant (works with LDS pointers) for the fallback kernel
template<int PH,int PL>
__device__ __forceinline__ void gate4(float2 v[16], const float2* __restrict__ g) {
    constexpr int mask = (1<<PH) | (1<<PL);
    #pragma unroll
    for (int base = 0; base < 16; ++base) {
        if (base & mask) continue;
        const int i0 = base, i1 = base | (1<<PL), i2 = base | (1<<PH), i3 = base | mask;
        float2 v0 = v[i0], v1 = v[i1], v2 = v[i2], v3 = v[i3];
        float2 w0, w1, w2, w3;
#define CROW(R, W)                                                                     \
        W.x = g[4*R+0].x*v0.x - g[4*R+0].y*v0.y + g[4*R+1].x*v1.x - g[4*R+1].y*v1.y    \
            + g[4*R+2].x*v2.x - g[4*R+2].y*v2.y + g[4*R+3].x*v3.x - g[4*R+3].y*v3.y;   \
        W.y = g[4*R+0].x*v0.y + g[4*R+0].y*v0.x + g[4*R+1].x*v1.y + g[4*R+1].y*v1.x    \
            + g[4*R+2].x*v2.y + g[4*R+2].y*v2.x + g[4*R+3].x*v3.y + g[4*R+3].y*v3.x;
        CROW(0, w0) CROW(1, w1) CROW(2, w2) CROW(3, w3)
#undef CROW
        v[i0] = w0; v[i1] = w1; v[i2] = w2; v[i3] = w3;
    }
}

// ============ kernel 2: full per-sample simulation, register-blocked ============
__global__ __launch_bounds__(NTH)
void sim(const float2* __restrict__ ws, float* __restrict__ out) {
    __shared__ float2 st[NSTATE];      // 128 KiB state
    const int b = blockIdx.x;
    const int t = threadIdx.x;
    const float2* G = ws;                                 // 13 fused variational 4x4
    const float2* F = ws + F_OFF + (size_t)b * 7 * 16;    // 7 per-sample ENC-fused 4x4

    float2 v[16];

    // ---- P1: register bits {13,12,11,10}; state = |0..0> directly ----
    {
        #pragma unroll
        for (int r = 0; r < 16; ++r) v[r] = make_float2(0.f, 0.f);
        if (t == 0) v[0].x = 1.f;
        gate4s<3,2>(v, F + 0*16);    // ENC0*G0 on (13,12)
        gate4s<1,0>(v, F + 1*16);    // ENC1*G1 on (11,10)
        gate4s<2,1>(v, G + 7*16);    // G7 on (12,11)
        const int pb = swz(t);                         // tb = t (bits 9..0)
        #pragma unroll
        for (int r = 0; r < 16; ++r) st[pb ^ prc<13,12,11,10>(r)] = v[r];
    }
    __syncthreads();

    // ---- P2: register bits {9,8,7,6} ----
    {
        const int tb = (t & 63) | ((t & 0x3C0) << 4);
        const int pb = swz(tb);
        #pragma unroll
        for (int r = 0; r < 16; ++r) v[r] = st[pb ^ prc<9,8,7,6>(r)];
        gate4s<3,2>(v, F + 2*16);    // ENC2*G2 on (9,8)
        gate4s<1,0>(v, F + 3*16);    // ENC3*G3 on (7,6)
        gate4s<2,1>(v, G + 9*16);    // G9 on (8,7)
        #pragma unroll
        for (int r = 0; r < 16; ++r) st[pb ^ prc<9,8,7,6>(r)] = v[r];
    }
    __syncthreads();

    // ---- P3: register bits {5,4,3,2} ----
    {
        const int tb = (t & 3) | ((t & 0x3FC) << 4);
        const int pb = swz(tb);
        #pragma unroll
        for (int r = 0; r < 16; ++r) v[r] = st[pb ^ prc<5,4,3,2>(r)];
        gate4s<3,2>(v, F + 4*16);    // ENC4*G4 on (5,4)
        gate4s<1,0>(v, F + 5*16);    // ENC5*G5 on (3,2)
        gate4s<2,1>(v, G + 11*16);   // G11 on (4,3)
        #pragma unroll
        for (int r = 0; r < 16; ++r) st[pb ^ prc<5,4,3,2>(r)] = v[r];
    }
    __syncthreads();

    // ---- P4: register bits {3,2,1,0} ----
    {
        const int tb = t << 4;
        const int pb = swz(tb);
        #pragma unroll
        for (int r = 0; r < 16; ++r) v[r] = st[pb ^ prc<3,2,1,0>(r)];
        gate4s<1,0>(v, F + 6*16);    // ENC6*G6 on (1,0)
        gate4s<2,1>(v, G + 12*16);   // G12 on (2,1)
        #pragma unroll
        for (int r = 0; r < 16; ++r) st[pb ^ prc<3,2,1,0>(r)] = v[r];
    }
    __syncthreads();

    // ---- P5: register bits {10,9,6,5}; reduce directly from registers ----
    int tb5;
    {
        tb5 = (t & 31) | ((t & 0x60) << 2) | ((t & 0x380) << 4);
        const int pb = swz(tb5);
        #pragma unroll
        for (int r = 0; r < 16; ++r) v[r] = st[pb ^ prc<10,9,6,5>(r)];
        gate4s<3,2>(v, G + 8*16);    // G8 on (10,9)
        gate4s<1,0>(v, G + 10*16);   // G10 on (6,5)
    }

    // ---- <Z>: per-thread partials from registers ----
    float pr[16], S = 0.f;
    #pragma unroll
    for (int r = 0; r < 16; ++r) { pr[r] = v[r].x * v[r].x + v[r].y * v[r].y; S += pr[r]; }
    float s5 = 0.f, s6 = 0.f, s9 = 0.f, s10 = 0.f;   // sums where that R-bit is 1
    #pragma unroll
    for (int r = 0; r < 16; ++r) {
        if (r & 1) s5  += pr[r];
        if (r & 2) s6  += pr[r];
        if (r & 4) s9  += pr[r];
        if (r & 8) s10 += pr[r];
    }
    float zq[WIRES];
    #pragma unroll
    for (int q = 0; q < WIRES; ++q) {
        const int bb = 13 - q;
        if      (bb == 10) zq[q] = S - 2.f * s10;
        else if (bb == 9)  zq[q] = S - 2.f * s9;
        else if (bb == 6)  zq[q] = S - 2.f * s6;
        else if (bb == 5)  zq[q] = S - 2.f * s5;
        else               zq[q] = ((tb5 >> bb) & 1) ? -S : S;
    }
    #pragma unroll
    for (int q = 0; q < WIRES; ++q) {
        #pragma unroll
        for (int off = 32; off >= 1; off >>= 1)
            zq[q] += __shfl_xor(zq[q], off, 64);
    }
    __syncthreads();                    // all P5 state reads done; reuse st as scratch
    float* part = (float*)st;
    const int lane = t & 63, wv = t >> 6;
    if (lane == 0) {
        #pragma unroll
        for (int q = 0; q < WIRES; ++q) part[wv * WIRES + q] = zq[q];
    }
    __syncthreads();
    if (t < WIRES) {
        float s = 0.f;
        #pragma unroll
        for (int w = 0; w < NTH / 64; ++w) s += part[w * WIRES + t];
        out[b * WIRES + t] = s;
    }
}

// ============ fallback (ws too small): ENC fused in-block via LDS ============
__global__ __launch_bounds__(NTH) void sim_fb(const float* __restrict__ inputs,
                                              const float2* __restrict__ gates,
                                              float* __restrict__ out) {
    __shared__ float2 st[NSTATE];
    __shared__ float2 Fsh[7 * 16];
    const int b = blockIdx.x;
    const int t = threadIdx.x;
    const float* inp = inputs + b * WIRES;

    if (t < 7) {
        const int j = t;
        float c1, s1, c2, s2;
        sincosf(inp[2*j]     * 0.5f, &s1, &c1);
        sincosf(inp[2*j + 1] * 0.5f, &s2, &c2);
        float E[16] = { c1*c2, -c1*s2, -s1*c2,  s1*s2,
                        c1*s2,  c1*c2, -s1*s2, -s1*c2,
                        s1*c2, -s1*s2,  c1*c2, -c1*s2,
                        s1*s2,  s1*c2,  c1*s2,  c1*c2 };
        const float2* Gj = gates + j * 16;
        #pragma unroll
        for (int r = 0; r < 4; ++r)
            #pragma unroll
            for (int c = 0; c < 4; ++c) {
                float2 a = make_float2(0.f, 0.f);
                #pragma unroll
                for (int k = 0; k < 4; ++k) {
                    a.x += Gj[r*4+k].x * E[k*4+c];
                    a.y += Gj[r*4+k].y * E[k*4+c];
                }
                Fsh[j*16 + r*4 + c] = a;
            }
    }
    __syncthreads();

    float2 v[16];
    {
        #pragma unroll
        for (int r = 0; r < 16; ++r) v[r] = make_float2(0.f, 0.f);
        if (t == 0) v[0].x = 1.f;
        gate4<3,2>(v, Fsh + 0*16);
        gate4<1,0>(v, Fsh + 1*16);
        gate4<2,1>(v, gates + 7*16);
        const int pb = swz(t);
        #pragma unroll
        for (int r = 0; r < 16; ++r) st[pb ^ prc<13,12,11,10>(r)] = v[r];
    }
    __syncthreads();
    {
        const int tb = (t & 63) | ((t & 0x3C0) << 4);
        const int pb = swz(tb);
        #pragma unroll
        for (int r = 0; r < 16; ++r) v[r] = st[pb ^ prc<9,8,7,6>(r)];
        gate4<3,2>(v, Fsh + 2*16);
        gate4<1,0>(v, Fsh + 3*16);
        gate4<2,1>(v, gates + 9*16);
        #pragma unroll
        for (int r = 0; r < 16; ++r) st[pb ^ prc<9,8,7,6>(r)] = v[r];
    }
    __syncthreads();
    {
        const int tb = (t & 3) | ((t & 0x3FC) << 4);
        const int pb = swz(tb);
        #pragma unroll
        for (int r = 0; r < 16; ++r) v[r] = st[pb ^ prc<5,4,3,2>(r)];
        gate4<3,2>(v, Fsh + 4*16);
        gate4<1,0>(v, Fsh + 5*16);
        gate4<2,1>(v, gates + 11*16);
        #pragma unroll
        for (int r = 0; r < 16; ++r) st[pb ^ prc<5,4,3,2>(r)] = v[r];
    }
    __syncthreads();
    {
        const int tb = t << 4;
        const int pb = swz(tb);
        #pragma unroll
        for (int r = 0; r < 16; ++r) v[r] = st[pb ^ prc<3,2,1,0>(r)];
        gate4<1,0>(v, Fsh + 6*16);
        gate4<2,1>(v, gates + 12*16);
        #pragma unroll
        for (int r = 0; r < 16; ++r) st[pb ^ prc<3,2,1,0>(r)] = v[r];
    }
    __syncthreads();
    int tb5;
    {
        tb5 = (t & 31) | ((t & 0x60) << 2) | ((t & 0x380) << 4);
        const int pb = swz(tb5);
        #pragma unroll
        for (int r = 0; r < 16; ++r) v[r] = st[pb ^ prc<10,9,6,5>(r)];
        gate4<3,2>(v, gates + 8*16);
        gate4<1,0>(v, gates + 10*16);
    }
    float pr[16], S = 0.f;
    #pragma unroll
    for (int r = 0; r < 16; ++r) { pr[r] = v[r].x * v[r].x + v[r].y * v[r].y; S += pr[r]; }
    float s5 = 0.f, s6 = 0.f, s9 = 0.f, s10 = 0.f;
    #pragma unroll
    for (int r = 0; r < 16; ++r) {
        if (r & 1) s5  += pr[r];
        if (r & 2) s6  += pr[r];
        if (r & 4) s9  += pr[r];
        if (r & 8) s10 += pr[r];
    }
    float zq[WIRES];
    #pragma unroll
    for (int q = 0; q < WIRES; ++q) {
        const int bb = 13 - q;
        if      (bb == 10) zq[q] = S - 2.f * s10;
        else if (bb == 9)  zq[q] = S - 2.f * s9;
        else if (bb == 6)  zq[q] = S - 2.f * s6;
        else if (bb == 5)  zq[q] = S - 2.f * s5;
        else               zq[q] = ((tb5 >> bb) & 1) ? -S : S;
    }
    #pragma unroll
    for (int q = 0; q < WIRES; ++q) {
        #pragma unroll
        for (int off = 32; off >= 1; off >>= 1)
            zq[q] += __shfl_xor(zq[q], off, 64);
    }
    __syncthreads();
    float* part = (float*)Fsh;
    const int lane = t & 63, wv = t >> 6;
    if (lane == 0) {
        #pragma unroll
        for (int q = 0; q < WIRES; ++q) part[wv * WIRES + q] = zq[q];
    }
    __syncthreads();
    if (t < WIRES) {
        float s = 0.f;
        #pragma unroll
        for (int w = 0; w < NTH / 64; ++w) s += part[w * WIRES + t];
        out[b * WIRES + t] = s;
    }
}

extern "C" void kernel_launch(void* const* d_in, const int* in_sizes, int n_in,
                              void* d_out, int out_size, void* d_ws, size_t ws_size,
                              hipStream_t stream) {
    const float* inputs = (const float*)d_in[0];
    const float* params = (const float*)d_in[1];
    float* out = (float*)d_out;
    float2* ws = (float2*)d_ws;

    const int batch = in_sizes[0] / WIRES;
    const size_t needed = (F_OFF + (size_t)batch * 7 * 16) * sizeof(float2);

    gate_prep<<<1, 64, 0, stream>>>(params, ws);
    if (ws_size >= needed) {
        enc_prep<<<(batch * 7 + 255) / 256, 256, 0, stream>>>(inputs, ws, batch);
        sim<<<batch, NTH, 0, stream>>>(ws, out);
    } else {
        sim_fb<<<batch, NTH, 0, stream>>>(inputs, ws, out);
    }
}

// Round 6
// 93.158 us; speedup vs baseline: 1.7972x; 1.7524x over previous
//
#include <hip/hip_runtime.h>

#define WIRES 14
#define NSTATE (1 << WIRES)   // 16384
#define NTH 1024
#define NVB 13                // variational blocks
#define F_OFF (NVB * 16)      // float2 offset of per-sample fused-ENC region in ws

typedef __attribute__((ext_vector_type(16))) float f16v;
typedef __attribute__((ext_vector_type(2)))  float v2f;

__device__ __forceinline__ float2 cmul(float2 a, float2 b) {
    return make_float2(a.x * b.x - a.y * b.y, a.x * b.y + a.y * b.x);
}

// ============ kernel 1: fuse each 10-gate variational block into one 4x4 ============
__global__ void gate_prep(const float* __restrict__ params, float2* __restrict__ G) {
    int k = threadIdx.x;
    if (k >= NVB) return;
    const float* p = params + k * 10;

    float2 U1[4], U2[4], U3[4], U4[4];
    auto rzrx = [](float trx, float trz, float2* U) {
        float cx, sx, cz, sz;
        sincosf(trx * 0.5f, &sx, &cx);
        sincosf(trz * 0.5f, &sz, &cz);
        float2 e0 = make_float2(cz, -sz);   // e^{-i h}
        float2 e1 = make_float2(cz,  sz);   // e^{+i h}
        U[0] = cmul(e0, make_float2(cx, 0.f));
        U[1] = cmul(e0, make_float2(0.f, -sx));
        U[2] = cmul(e1, make_float2(0.f, -sx));
        U[3] = cmul(e1, make_float2(cx, 0.f));
    };
    rzrx(p[0], p[1], U1);   // q1, first
    rzrx(p[2], p[3], U2);   // q2, first
    rzrx(p[5], p[6], U3);   // q1, second
    rzrx(p[7], p[8], U4);   // q2, second

    float2 K12[16], K34[16];
    for (int r1 = 0; r1 < 2; ++r1)
        for (int r2 = 0; r2 < 2; ++r2)
            for (int c1 = 0; c1 < 2; ++c1)
                for (int c2 = 0; c2 < 2; ++c2) {
                    int idx = (r1 * 2 + r2) * 4 + (c1 * 2 + c2);
                    K12[idx] = cmul(U1[r1 * 2 + c1], U2[r2 * 2 + c2]);
                    K34[idx] = cmul(U3[r1 * 2 + c1], U4[r2 * 2 + c2]);
                }

    float2 C1[16], C2[16];
    for (int i = 0; i < 16; ++i) { C1[i] = make_float2(0.f, 0.f); C2[i] = make_float2(0.f, 0.f); }
    {
        float c, s;
        sincosf(p[4] * 0.5f, &s, &c);        // CRY ctrl=q1(high local bit), tgt=q2
        C1[0]  = make_float2(1.f, 0.f); C1[5]  = make_float2(1.f, 0.f);
        C1[10] = make_float2(c, 0.f);   C1[11] = make_float2(-s, 0.f);
        C1[14] = make_float2(s, 0.f);   C1[15] = make_float2(c, 0.f);
        sincosf(p[9] * 0.5f, &s, &c);        // CRY ctrl=q2(low local bit), tgt=q1
        C2[0]  = make_float2(1.f, 0.f); C2[10] = make_float2(1.f, 0.f);
        C2[5]  = make_float2(c, 0.f);   C2[7]  = make_float2(-s, 0.f);
        C2[13] = make_float2(s, 0.f);   C2[15] = make_float2(c, 0.f);
    }

    float2 T1[16], T2[16], Gk[16];
    for (int r = 0; r < 4; ++r)
        for (int c = 0; c < 4; ++c) {
            float2 a = make_float2(0.f, 0.f);
            for (int j = 0; j < 4; ++j) { float2 m = cmul(C1[r*4+j], K12[j*4+c]); a.x += m.x; a.y += m.y; }
            T1[r*4+c] = a;
        }
    for (int r = 0; r < 4; ++r)
        for (int c = 0; c < 4; ++c) {
            float2 a = make_float2(0.f, 0.f);
            for (int j = 0; j < 4; ++j) { float2 m = cmul(K34[r*4+j], T1[j*4+c]); a.x += m.x; a.y += m.y; }
            T2[r*4+c] = a;
        }
    for (int r = 0; r < 4; ++r)
        for (int c = 0; c < 4; ++c) {
            float2 a = make_float2(0.f, 0.f);
            for (int j = 0; j < 4; ++j) { float2 m = cmul(C2[r*4+j], T2[j*4+c]); a.x += m.x; a.y += m.y; }
            Gk[r*4+c] = a;
        }
    for (int i = 0; i < 16; ++i) G[k * 16 + i] = Gk[i];
}

// ============ kernel 1b: per-sample fuse ENC pair j into layer-1 block: F = G_j * E ============
__global__ void enc_prep(const float* __restrict__ inputs, float2* __restrict__ ws, int batch) {
    int idx = blockIdx.x * blockDim.x + threadIdx.x;
    if (idx >= batch * 7) return;
    const int b = idx / 7, j = idx % 7;
    float c1, s1, c2, s2;
    sincosf(inputs[b * WIRES + 2*j]     * 0.5f, &s1, &c1);
    sincosf(inputs[b * WIRES + 2*j + 1] * 0.5f, &s2, &c2);
    float E[16] = { c1*c2, -c1*s2, -s1*c2,  s1*s2,
                    c1*s2,  c1*c2, -s1*s2, -s1*c2,
                    s1*c2, -s1*s2,  c1*c2, -c1*s2,
                    s1*s2,  s1*c2,  c1*s2,  c1*c2 };
    const float2* Gj = ws + j * 16;
    float2* F = ws + F_OFF + (size_t)(b * 7 + j) * 16;
    #pragma unroll
    for (int r = 0; r < 4; ++r)
        #pragma unroll
        for (int c = 0; c < 4; ++c) {
            float2 a = make_float2(0.f, 0.f);
            #pragma unroll
            for (int k = 0; k < 4; ++k) {
                a.x += Gj[r*4+k].x * E[k*4+c];
                a.y += Gj[r*4+k].y * E[k*4+c];
            }
            F[r*4+c] = a;
        }
}

// ============ sim kernel helpers ============

// GF(2)-linear LDS swizzle on float2 index
__device__ __forceinline__ int swz(int i) { return i ^ ((i >> 4) & 15); }

// compile-time: scatter r's 4 bits to global bit positions, then swizzle
template<int B3,int B2,int B1,int B0>
constexpr int prc(int r) {
    int s = ((r&1)?(1<<B0):0) | ((r&2)?(1<<B1):0) | ((r&4)?(1<<B2):0) | ((r&8)?(1<<B3):0);
    return s ^ ((s >> 4) & 15);
}

// scalar-load 32 floats (one 4x4 complex gate) from a wave-uniform global
// address into SGPRs: zero VGPR cost for gate coefficients.
__device__ __forceinline__ void sload32(const float2* p, f16v& lo, f16v& hi) {
    asm volatile("s_load_dwordx16 %0, %2, 0x0\n\t"
                 "s_load_dwordx16 %1, %2, 0x40\n\t"
                 "s_waitcnt lgkmcnt(0)"
                 : "=&s"(lo), "=&s"(hi)
                 : "s"(p));
}

// ---- packed complex arithmetic: coeff (a,b) sits in an SGPR pair; op_sel/neg
// modifiers implement w += (a+ib)*v in TWO v_pk instructions:
//   lo: a*vx - b*vy ; hi: a*vy + b*vx
__device__ __forceinline__ void cmul_pk(v2f& w, v2f ab, v2f v) {
    asm("v_pk_mul_f32 %0, %1, %2 op_sel:[0,0] op_sel_hi:[0,1]\n\t"
        "v_pk_fma_f32 %0, %1, %2, %0 op_sel:[1,1,0] op_sel_hi:[1,0,1] neg_lo:[1,0,0]"
        : "=&v"(w) : "s"(ab), "v"(v));
}
__device__ __forceinline__ void cfma_pk(v2f& w, v2f ab, v2f v) {
    asm("v_pk_fma_f32 %0, %1, %2, %0 op_sel:[0,0,0] op_sel_hi:[0,1,1]\n\t"
        "v_pk_fma_f32 %0, %1, %2, %0 op_sel:[1,1,0] op_sel_hi:[1,0,1] neg_lo:[1,0,0]"
        : "+v"(w) : "s"(ab), "v"(v));
}

// complex 4x4 gate on local register-bit pair (PH=high, PL=low); coeffs from
// SGPRs, math in packed-f32 (128 VOP3P instrs per gate application).
template<int PH,int PL>
__device__ __forceinline__ void gate4pk(v2f v[16], const float2* __restrict__ gp) {
    f16v lo, hi;
    sload32(gp, lo, hi);
    constexpr int mask = (1<<PH) | (1<<PL);
    #pragma unroll
    for (int base = 0; base < 16; ++base) {
        if (base & mask) continue;
        const int i0 = base, i1 = base | (1<<PL), i2 = base | (1<<PH), i3 = base | mask;
        v2f v0 = v[i0], v1 = v[i1], v2 = v[i2], v3 = v[i3];
        v2f w0, w1, w2, w3;
#define CC(V, J) ((v2f){V[2*(J)], V[2*(J)+1]})
        cmul_pk(w0, CC(lo,0), v0); cfma_pk(w0, CC(lo,1), v1); cfma_pk(w0, CC(lo,2), v2); cfma_pk(w0, CC(lo,3), v3);
        cmul_pk(w1, CC(lo,4), v0); cfma_pk(w1, CC(lo,5), v1); cfma_pk(w1, CC(lo,6), v2); cfma_pk(w1, CC(lo,7), v3);
        cmul_pk(w2, CC(hi,0), v0); cfma_pk(w2, CC(hi,1), v1); cfma_pk(w2, CC(hi,2), v2); cfma_pk(w2, CC(hi,3), v3);
        cmul_pk(w3, CC(hi,4), v0); cfma_pk(w3, CC(hi,5), v1); cfma_pk(w3, CC(hi,6), v2); cfma_pk(w3, CC(hi,7), v3);
#undef CC
        v[i0] = w0; v[i1] = w1; v[i2] = w2; v[i3] = w3;
    }
}

// plain-VGPR scalar variant (works with LDS pointers) for the fallback kernel
template<int PH,int PL>
__device__ __forceinline__ void gate4(float2 v[16], const float2* __restrict__ g) {
    constexpr int mask = (1<<PH) | (1<<PL);
    #pragma unroll
    for (int base = 0; base < 16; ++base) {
        if (base & mask) continue;
        const int i0 = base, i1 = base | (1<<PL), i2 = base | (1<<PH), i3 = base | mask;
        float2 v0 = v[i0], v1 = v[i1], v2 = v[i2], v3 = v[i3];
        float2 w0, w1, w2, w3;
#define CROW(R, W)                                                                     \
        W.x = g[4*R+0].x*v0.x - g[4*R+0].y*v0.y + g[4*R+1].x*v1.x - g[4*R+1].y*v1.y    \
            + g[4*R+2].x*v2.x - g[4*R+2].y*v2.y + g[4*R+3].x*v3.x - g[4*R+3].y*v3.y;   \
        W.y = g[4*R+0].x*v0.y + g[4*R+0].y*v0.x + g[4*R+1].x*v1.y + g[4*R+1].y*v1.x    \
            + g[4*R+2].x*v2.y + g[4*R+2].y*v2.x + g[4*R+3].x*v3.y + g[4*R+3].y*v3.x;
        CROW(0, w0) CROW(1, w1) CROW(2, w2) CROW(3, w3)
#undef CROW
        v[i0] = w0; v[i1] = w1; v[i2] = w2; v[i3] = w3;
    }
}

// ============ kernel 2: full per-sample simulation, register-blocked, packed math ============
__global__ __launch_bounds__(NTH)
void sim(const v2f* __restrict__ ws, float* __restrict__ out) {
    __shared__ v2f st[NSTATE];      // 128 KiB state
    const int b = blockIdx.x;
    const int t = threadIdx.x;
    const float2* G = (const float2*)ws;                       // 13 fused variational 4x4
    const float2* F = (const float2*)(ws + F_OFF) + (size_t)b * 7 * 16;  // 7 per-sample ENC-fused

    v2f v[16];

    // ---- P1: register bits {13,12,11,10}; state = |0..0> directly ----
    {
        #pragma unroll
        for (int r = 0; r < 16; ++r) v[r] = (v2f){0.f, 0.f};
        if (t == 0) v[0] = (v2f){1.f, 0.f};
        gate4pk<3,2>(v, F + 0*16);    // ENC0*G0 on (13,12)
        gate4pk<1,0>(v, F + 1*16);    // ENC1*G1 on (11,10)
        gate4pk<2,1>(v, G + 7*16);    // G7 on (12,11)
        const int pb = swz(t);                         // tb = t (bits 9..0)
        #pragma unroll
        for (int r = 0; r < 16; ++r) st[pb ^ prc<13,12,11,10>(r)] = v[r];
    }
    __syncthreads();

    // ---- P2: register bits {9,8,7,6} ----
    {
        const int tb = (t & 63) | ((t & 0x3C0) << 4);
        const int pb = swz(tb);
        #pragma unroll
        for (int r = 0; r < 16; ++r) v[r] = st[pb ^ prc<9,8,7,6>(r)];
        gate4pk<3,2>(v, F + 2*16);    // ENC2*G2 on (9,8)
        gate4pk<1,0>(v, F + 3*16);    // ENC3*G3 on (7,6)
        gate4pk<2,1>(v, G + 9*16);    // G9 on (8,7)
        #pragma unroll
        for (int r = 0; r < 16; ++r) st[pb ^ prc<9,8,7,6>(r)] = v[r];
    }
    __syncthreads();

    // ---- P3: register bits {5,4,3,2} ----
    {
        const int tb = (t & 3) | ((t & 0x3FC) << 4);
        const int pb = swz(tb);
        #pragma unroll
        for (int r = 0; r < 16; ++r) v[r] = st[pb ^ prc<5,4,3,2>(r)];
        gate4pk<3,2>(v, F + 4*16);    // ENC4*G4 on (5,4)
        gate4pk<1,0>(v, F + 5*16);    // ENC5*G5 on (3,2)
        gate4pk<2,1>(v, G + 11*16);   // G11 on (4,3)
        #pragma unroll
        for (int r = 0; r < 16; ++r) st[pb ^ prc<5,4,3,2>(r)] = v[r];
    }
    __syncthreads();

    // ---- P4: register bits {3,2,1,0} ----
    {
        const int tb = t << 4;
        const int pb = swz(tb);
        #pragma unroll
        for (int r = 0; r < 16; ++r) v[r] = st[pb ^ prc<3,2,1,0>(r)];
        gate4pk<1,0>(v, F + 6*16);    // ENC6*G6 on (1,0)
        gate4pk<2,1>(v, G + 12*16);   // G12 on (2,1)
        #pragma unroll
        for (int r = 0; r < 16; ++r) st[pb ^ prc<3,2,1,0>(r)] = v[r];
    }
    __syncthreads();

    // ---- P5: register bits {10,9,6,5}; reduce directly from registers ----
    int tb5;
    {
        tb5 = (t & 31) | ((t & 0x60) << 2) | ((t & 0x380) << 4);
        const int pb = swz(tb5);
        #pragma unroll
        for (int r = 0; r < 16; ++r) v[r] = st[pb ^ prc<10,9,6,5>(r)];
        gate4pk<3,2>(v, G + 8*16);    // G8 on (10,9)
        gate4pk<1,0>(v, G + 10*16);   // G10 on (6,5)
    }

    // ---- <Z>: 5 accumulators while v dies (no pr[] array -> no spill) ----
    float S = 0.f, s5 = 0.f, s6 = 0.f, s9 = 0.f, s10 = 0.f;
    #pragma unroll
    for (int r = 0; r < 16; ++r) {
        float p = v[r][0] * v[r][0] + v[r][1] * v[r][1];
        S += p;
        if (r & 1) s5  += p;
        if (r & 2) s6  += p;
        if (r & 4) s9  += p;
        if (r & 8) s10 += p;
    }
    float zq[WIRES];
    #pragma unroll
    for (int q = 0; q < WIRES; ++q) {
        const int bb = 13 - q;
        if      (bb == 10) zq[q] = S - 2.f * s10;
        else if (bb == 9)  zq[q] = S - 2.f * s9;
        else if (bb == 6)  zq[q] = S - 2.f * s6;
        else if (bb == 5)  zq[q] = S - 2.f * s5;
        else               zq[q] = ((tb5 >> bb) & 1) ? -S : S;
    }
    #pragma unroll
    for (int q = 0; q < WIRES; ++q) {
        #pragma unroll
        for (int off = 32; off >= 1; off >>= 1)
            zq[q] += __shfl_xor(zq[q], off, 64);
    }
    __syncthreads();                    // all P5 state reads done; reuse st as scratch
    float* part = (float*)st;
    const int lane = t & 63, wv = t >> 6;
    if (lane == 0) {
        #pragma unroll
        for (int q = 0; q < WIRES; ++q) part[wv * WIRES + q] = zq[q];
    }
    __syncthreads();
    if (t < WIRES) {
        float s = 0.f;
        #pragma unroll
        for (int w = 0; w < NTH / 64; ++w) s += part[w * WIRES + t];
        out[b * WIRES + t] = s;
    }
}

// ============ fallback (ws too small): ENC fused in-block via LDS, scalar math ============
__global__ __launch_bounds__(NTH) void sim_fb(const float* __restrict__ inputs,
                                              const float2* __restrict__ gates,
                                              float* __restrict__ out) {
    __shared__ float2 st[NSTATE];
    __shared__ float2 Fsh[7 * 16];
    const int b = blockIdx.x;
    const int t = threadIdx.x;
    const float* inp = inputs + b * WIRES;

    if (t < 7) {
        const int j = t;
        float c1, s1, c2, s2;
        sincosf(inp[2*j]     * 0.5f, &s1, &c1);
        sincosf(inp[2*j + 1] * 0.5f, &s2, &c2);
        float E[16] = { c1*c2, -c1*s2, -s1*c2,  s1*s2,
                        c1*s2,  c1*c2, -s1*s2, -s1*c2,
                        s1*c2, -s1*s2,  c1*c2, -c1*s2,
                        s1*s2,  s1*c2,  c1*s2,  c1*c2 };
        const float2* Gj = gates + j * 16;
        #pragma unroll
        for (int r = 0; r < 4; ++r)
            #pragma unroll
            for (int c = 0; c < 4; ++c) {
                float2 a = make_float2(0.f, 0.f);
                #pragma unroll
                for (int k = 0; k < 4; ++k) {
                    a.x += Gj[r*4+k].x * E[k*4+c];
                    a.y += Gj[r*4+k].y * E[k*4+c];
                }
                Fsh[j*16 + r*4 + c] = a;
            }
    }
    __syncthreads();

    float2 v[16];
    {
        #pragma unroll
        for (int r = 0; r < 16; ++r) v[r] = make_float2(0.f, 0.f);
        if (t == 0) v[0].x = 1.f;
        gate4<3,2>(v, Fsh + 0*16);
        gate4<1,0>(v, Fsh + 1*16);
        gate4<2,1>(v, gates + 7*16);
        const int pb = swz(t);
        #pragma unroll
        for (int r = 0; r < 16; ++r) st[pb ^ prc<13,12,11,10>(r)] = v[r];
    }
    __syncthreads();
    {
        const int tb = (t & 63) | ((t & 0x3C0) << 4);
        const int pb = swz(tb);
        #pragma unroll
        for (int r = 0; r < 16; ++r) v[r] = st[pb ^ prc<9,8,7,6>(r)];
        gate4<3,2>(v, Fsh + 2*16);
        gate4<1,0>(v, Fsh + 3*16);
        gate4<2,1>(v, gates + 9*16);
        #pragma unroll
        for (int r = 0; r < 16; ++r) st[pb ^ prc<9,8,7,6>(r)] = v[r];
    }
    __syncthreads();
    {
        const int tb = (t & 3) | ((t & 0x3FC) << 4);
        const int pb = swz(tb);
        #pragma unroll
        for (int r = 0; r < 16; ++r) v[r] = st[pb ^ prc<5,4,3,2>(r)];
        gate4<3,2>(v, Fsh + 4*16);
        gate4<1,0>(v, Fsh + 5*16);
        gate4<2,1>(v, gates + 11*16);
        #pragma unroll
        for (int r = 0; r < 16; ++r) st[pb ^ prc<5,4,3,2>(r)] = v[r];
    }
    __syncthreads();
    {
        const int tb = t << 4;
        const int pb = swz(tb);
        #pragma unroll
        for (int r = 0; r < 16; ++r) v[r] = st[pb ^ prc<3,2,1,0>(r)];
        gate4<1,0>(v, Fsh + 6*16);
        gate4<2,1>(v, gates + 12*16);
        #pragma unroll
        for (int r = 0; r < 16; ++r) st[pb ^ prc<3,2,1,0>(r)] = v[r];
    }
    __syncthreads();
    int tb5;
    {
        tb5 = (t & 31) | ((t & 0x60) << 2) | ((t & 0x380) << 4);
        const int pb = swz(tb5);
        #pragma unroll
        for (int r = 0; r < 16; ++r) v[r] = st[pb ^ prc<10,9,6,5>(r)];
        gate4<3,2>(v, gates + 8*16);
        gate4<1,0>(v, gates + 10*16);
    }
    float S = 0.f, s5 = 0.f, s6 = 0.f, s9 = 0.f, s10 = 0.f;
    #pragma unroll
    for (int r = 0; r < 16; ++r) {
        float p = v[r].x * v[r].x + v[r].y * v[r].y;
        S += p;
        if (r & 1) s5  += p;
        if (r & 2) s6  += p;
        if (r & 4) s9  += p;
        if (r & 8) s10 += p;
    }
    float zq[WIRES];
    #pragma unroll
    for (int q = 0; q < WIRES; ++q) {
        const int bb = 13 - q;
        if      (bb == 10) zq[q] = S - 2.f * s10;
        else if (bb == 9)  zq[q] = S - 2.f * s9;
        else if (bb == 6)  zq[q] = S - 2.f * s6;
        else if (bb == 5)  zq[q] = S - 2.f * s5;
        else               zq[q] = ((tb5 >> bb) & 1) ? -S : S;
    }
    #pragma unroll
    for (int q = 0; q < WIRES; ++q) {
        #pragma unroll
        for (int off = 32; off >= 1; off >>= 1)
            zq[q] += __shfl_xor(zq[q], off, 64);
    }
    __syncthreads();
    float* part = (float*)Fsh;
    const int lane = t & 63, wv = t >> 6;
    if (lane == 0) {
        #pragma unroll
        for (int q = 0; q < WIRES; ++q) part[wv * WIRES + q] = zq[q];
    }
    __syncthreads();
    if (t < WIRES) {
        float s = 0.f;
        #pragma unroll
        for (int w = 0; w < NTH / 64; ++w) s += part[w * WIRES + t];
        out[b * WIRES + t] = s;
    }
}

extern "C" void kernel_launch(void* const* d_in, const int* in_sizes, int n_in,
                              void* d_out, int out_size, void* d_ws, size_t ws_size,
                              hipStream_t stream) {
    const float* inputs = (const float*)d_in[0];
    const float* params = (const float*)d_in[1];
    float* out = (float*)d_out;
    float2* ws = (float2*)d_ws;

    const int batch = in_sizes[0] / WIRES;
    const size_t needed = (F_OFF + (size_t)batch * 7 * 16) * sizeof(float2);

    gate_prep<<<1, 64, 0, stream>>>(params, ws);
    if (ws_size >= needed) {
        enc_prep<<<(batch * 7 + 255) / 256, 256, 0, stream>>>(inputs, ws, batch);
        sim<<<batch, NTH, 0, stream>>>((const v2f*)ws, out);
    } else {
        sim_fb<<<batch, NTH, 0, stream>>>(inputs, ws, out);
    }
}

// Round 7
// 90.918 us; speedup vs baseline: 1.8415x; 1.0246x over previous
//
#include <hip/hip_runtime.h>

#define WIRES 14
#define NSTATE (1 << WIRES)   // 16384
#define NTH 1024
#define NVB 13                // variational blocks
#define F_OFF (NVB * 16)      // float2 offset of per-sample fused-ENC region in ws

typedef __attribute__((ext_vector_type(16))) float f16v;
typedef __attribute__((ext_vector_type(2)))  float v2f;

__device__ __forceinline__ float2 cmul(float2 a, float2 b) {
    return make_float2(a.x * b.x - a.y * b.y, a.x * b.y + a.y * b.x);
}

// ============ kernel 1: fuse each 10-gate variational block into one 4x4 ============
__global__ void gate_prep(const float* __restrict__ params, float2* __restrict__ G) {
    int k = threadIdx.x;
    if (k >= NVB) return;
    const float* p = params + k * 10;

    float2 U1[4], U2[4], U3[4], U4[4];
    auto rzrx = [](float trx, float trz, float2* U) {
        float cx, sx, cz, sz;
        sincosf(trx * 0.5f, &sx, &cx);
        sincosf(trz * 0.5f, &sz, &cz);
        float2 e0 = make_float2(cz, -sz);   // e^{-i h}
        float2 e1 = make_float2(cz,  sz);   // e^{+i h}
        U[0] = cmul(e0, make_float2(cx, 0.f));
        U[1] = cmul(e0, make_float2(0.f, -sx));
        U[2] = cmul(e1, make_float2(0.f, -sx));
        U[3] = cmul(e1, make_float2(cx, 0.f));
    };
    rzrx(p[0], p[1], U1);   // q1, first
    rzrx(p[2], p[3], U2);   // q2, first
    rzrx(p[5], p[6], U3);   // q1, second
    rzrx(p[7], p[8], U4);   // q2, second

    float2 K12[16], K34[16];
    for (int r1 = 0; r1 < 2; ++r1)
        for (int r2 = 0; r2 < 2; ++r2)
            for (int c1 = 0; c1 < 2; ++c1)
                for (int c2 = 0; c2 < 2; ++c2) {
                    int idx = (r1 * 2 + r2) * 4 + (c1 * 2 + c2);
                    K12[idx] = cmul(U1[r1 * 2 + c1], U2[r2 * 2 + c2]);
                    K34[idx] = cmul(U3[r1 * 2 + c1], U4[r2 * 2 + c2]);
                }

    float2 C1[16], C2[16];
    for (int i = 0; i < 16; ++i) { C1[i] = make_float2(0.f, 0.f); C2[i] = make_float2(0.f, 0.f); }
    {
        float c, s;
        sincosf(p[4] * 0.5f, &s, &c);        // CRY ctrl=q1(high local bit), tgt=q2
        C1[0]  = make_float2(1.f, 0.f); C1[5]  = make_float2(1.f, 0.f);
        C1[10] = make_float2(c, 0.f);   C1[11] = make_float2(-s, 0.f);
        C1[14] = make_float2(s, 0.f);   C1[15] = make_float2(c, 0.f);
        sincosf(p[9] * 0.5f, &s, &c);        // CRY ctrl=q2(low local bit), tgt=q1
        C2[0]  = make_float2(1.f, 0.f); C2[10] = make_float2(1.f, 0.f);
        C2[5]  = make_float2(c, 0.f);   C2[7]  = make_float2(-s, 0.f);
        C2[13] = make_float2(s, 0.f);   C2[15] = make_float2(c, 0.f);
    }

    float2 T1[16], T2[16], Gk[16];
    for (int r = 0; r < 4; ++r)
        for (int c = 0; c < 4; ++c) {
            float2 a = make_float2(0.f, 0.f);
            for (int j = 0; j < 4; ++j) { float2 m = cmul(C1[r*4+j], K12[j*4+c]); a.x += m.x; a.y += m.y; }
            T1[r*4+c] = a;
        }
    for (int r = 0; r < 4; ++r)
        for (int c = 0; c < 4; ++c) {
            float2 a = make_float2(0.f, 0.f);
            for (int j = 0; j < 4; ++j) { float2 m = cmul(K34[r*4+j], T1[j*4+c]); a.x += m.x; a.y += m.y; }
            T2[r*4+c] = a;
        }
    for (int r = 0; r < 4; ++r)
        for (int c = 0; c < 4; ++c) {
            float2 a = make_float2(0.f, 0.f);
            for (int j = 0; j < 4; ++j) { float2 m = cmul(C2[r*4+j], T2[j*4+c]); a.x += m.x; a.y += m.y; }
            Gk[r*4+c] = a;
        }
    for (int i = 0; i < 16; ++i) G[k * 16 + i] = Gk[i];
}

// ============ kernel 1b: per-sample fuse ENC pair j into layer-1 block: F = G_j * E ============
__global__ void enc_prep(const float* __restrict__ inputs, float2* __restrict__ ws, int batch) {
    int idx = blockIdx.x * blockDim.x + threadIdx.x;
    if (idx >= batch * 7) return;
    const int b = idx / 7, j = idx % 7;
    float c1, s1, c2, s2;
    sincosf(inputs[b * WIRES + 2*j]     * 0.5f, &s1, &c1);
    sincosf(inputs[b * WIRES + 2*j + 1] * 0.5f, &s2, &c2);
    float E[16] = { c1*c2, -c1*s2, -s1*c2,  s1*s2,
                    c1*s2,  c1*c2, -s1*s2, -s1*c2,
                    s1*c2, -s1*s2,  c1*c2, -c1*s2,
                    s1*s2,  s1*c2,  c1*s2,  c1*c2 };
    const float2* Gj = ws + j * 16;
    float2* F = ws + F_OFF + (size_t)(b * 7 + j) * 16;
    #pragma unroll
    for (int r = 0; r < 4; ++r)
        #pragma unroll
        for (int c = 0; c < 4; ++c) {
            float2 a = make_float2(0.f, 0.f);
            #pragma unroll
            for (int k = 0; k < 4; ++k) {
                a.x += Gj[r*4+k].x * E[k*4+c];
                a.y += Gj[r*4+k].y * E[k*4+c];
            }
            F[r*4+c] = a;
        }
}

// ============ sim kernel helpers ============

// GF(2)-linear LDS swizzle on float2 index (folds bits 4..7 into 0..3)
__device__ __forceinline__ int swz(int i) { return i ^ ((i >> 4) & 15); }

// compile-time: scatter r's 4 bits to global state-bit positions, then swizzle
template<int B3,int B2,int B1,int B0>
constexpr int prc(int r) {
    int s = ((r&1)?(1<<B0):0) | ((r&2)?(1<<B1):0) | ((r&4)?(1<<B2):0) | ((r&8)?(1<<B3):0);
    return s ^ ((s >> 4) & 15);
}

// scalar-load 32 floats (one 4x4 complex gate) from a wave-uniform global
// address into SGPRs: zero VGPR cost for gate coefficients.
__device__ __forceinline__ void sload32(const float2* p, f16v& lo, f16v& hi) {
    asm volatile("s_load_dwordx16 %0, %2, 0x0\n\t"
                 "s_load_dwordx16 %1, %2, 0x40\n\t"
                 "s_waitcnt lgkmcnt(0)"
                 : "=&s"(lo), "=&s"(hi)
                 : "s"(p));
}

// ---- packed complex arithmetic: coeff (a,b) in an SGPR pair; op_sel/neg
// modifiers implement w += (a+ib)*v in TWO v_pk instructions.
__device__ __forceinline__ void cmul_pk(v2f& w, v2f ab, v2f v) {
    asm("v_pk_mul_f32 %0, %1, %2 op_sel:[0,0] op_sel_hi:[0,1]\n\t"
        "v_pk_fma_f32 %0, %1, %2, %0 op_sel:[1,1,0] op_sel_hi:[1,0,1] neg_lo:[1,0,0]"
        : "=&v"(w) : "s"(ab), "v"(v));
}
__device__ __forceinline__ void cfma_pk(v2f& w, v2f ab, v2f v) {
    asm("v_pk_fma_f32 %0, %1, %2, %0 op_sel:[0,0,0] op_sel_hi:[0,1,1]\n\t"
        "v_pk_fma_f32 %0, %1, %2, %0 op_sel:[1,1,0] op_sel_hi:[1,0,1] neg_lo:[1,0,0]"
        : "+v"(w) : "s"(ab), "v"(v));
}

// complex 4x4 gate on local register-bit pair (PH = reg bit of the HIGH state
// bit, PL = reg bit of the LOW state bit); coeffs from SGPRs, packed-f32 math.
template<int PH,int PL>
__device__ __forceinline__ void gate4pk(v2f v[16], const float2* __restrict__ gp) {
    f16v lo, hi;
    sload32(gp, lo, hi);
    constexpr int mask = (1<<PH) | (1<<PL);
    #pragma unroll
    for (int base = 0; base < 16; ++base) {
        if (base & mask) continue;
        const int i0 = base, i1 = base | (1<<PL), i2 = base | (1<<PH), i3 = base | mask;
        v2f v0 = v[i0], v1 = v[i1], v2 = v[i2], v3 = v[i3];
        v2f w0, w1, w2, w3;
#define CC(V, J) ((v2f){V[2*(J)], V[2*(J)+1]})
        cmul_pk(w0, CC(lo,0), v0); cfma_pk(w0, CC(lo,1), v1); cfma_pk(w0, CC(lo,2), v2); cfma_pk(w0, CC(lo,3), v3);
        cmul_pk(w1, CC(lo,4), v0); cfma_pk(w1, CC(lo,5), v1); cfma_pk(w1, CC(lo,6), v2); cfma_pk(w1, CC(lo,7), v3);
        cmul_pk(w2, CC(hi,0), v0); cfma_pk(w2, CC(hi,1), v1); cfma_pk(w2, CC(hi,2), v2); cfma_pk(w2, CC(hi,3), v3);
        cmul_pk(w3, CC(hi,4), v0); cfma_pk(w3, CC(hi,5), v1); cfma_pk(w3, CC(hi,6), v2); cfma_pk(w3, CC(hi,7), v3);
#undef CC
        v[i0] = w0; v[i1] = w1; v[i2] = w2; v[i3] = w3;
    }
}

// 1-bit exchange: reg bit 0 <-> lane bit 5 (half-wave). For each reg pair
// (r, r|1): new v[r].hiLanes = old v[r|1].loLanes and vice versa — exactly
// v_permlane32_swap_b32 (swaps vdst's upper 32 lanes with vsrc's lower 32).
__device__ __forceinline__ void xchg_halfwave(v2f v[16]) {
    #pragma unroll
    for (int r = 0; r < 16; r += 2) {
        asm volatile("v_permlane32_swap_b32 %0, %1" : "+v"(v[r][0]), "+v"(v[r+1][0]));
        asm volatile("v_permlane32_swap_b32 %0, %1" : "+v"(v[r][1]), "+v"(v[r+1][1]));
    }
}

// plain-VGPR scalar variant (works with LDS pointers) for the fallback kernel
template<int PH,int PL>
__device__ __forceinline__ void gate4(float2 v[16], const float2* __restrict__ g) {
    constexpr int mask = (1<<PH) | (1<<PL);
    #pragma unroll
    for (int base = 0; base < 16; ++base) {
        if (base & mask) continue;
        const int i0 = base, i1 = base | (1<<PL), i2 = base | (1<<PH), i3 = base | mask;
        float2 v0 = v[i0], v1 = v[i1], v2 = v[i2], v3 = v[i3];
        float2 w0, w1, w2, w3;
#define CROW(R, W)                                                                     \
        W.x = g[4*R+0].x*v0.x - g[4*R+0].y*v0.y + g[4*R+1].x*v1.x - g[4*R+1].y*v1.y    \
            + g[4*R+2].x*v2.x - g[4*R+2].y*v2.y + g[4*R+3].x*v3.x - g[4*R+3].y*v3.y;   \
        W.y = g[4*R+0].x*v0.y + g[4*R+0].y*v0.x + g[4*R+1].x*v1.y + g[4*R+1].y*v1.x    \
            + g[4*R+2].x*v2.y + g[4*R+2].y*v2.x + g[4*R+3].x*v3.y + g[4*R+3].y*v3.x;
        CROW(0, w0) CROW(1, w1) CROW(2, w2) CROW(3, w3)
#undef CROW
        v[i0] = w0; v[i1] = w1; v[i2] = w2; v[i3] = w3;
    }
}

// ============ kernel 2: 4-phase register-blocked simulation ============
// Phase layouts (state bit -> location). Wave bits of P3-write == P4-read
// ({10,11,12,13}), so that transition needs no __syncthreads (same-wave LDS
// ops are processed in order).
__global__ __launch_bounds__(NTH)
void sim(const v2f* __restrict__ ws, float* __restrict__ out) {
    __shared__ v2f st[NSTATE];      // 128 KiB state
    const int b = blockIdx.x;
    const int t = threadIdx.x;
    const float2* G = (const float2*)ws;
    const float2* F = (const float2*)(ws + F_OFF) + (size_t)b * 7 * 16;

    v2f v[16];

    // ---- P1: regs r0..r3 -> state {10,11,12,13}; t0..t9 -> state 0..9 ----
    {
        #pragma unroll
        for (int r = 0; r < 16; ++r) v[r] = (v2f){0.f, 0.f};
        if (t == 0) v[0] = (v2f){1.f, 0.f};
        gate4pk<3,2>(v, F + 0*16);    // (13,12)
        gate4pk<1,0>(v, F + 1*16);    // (11,10)
        gate4pk<2,1>(v, G + 7*16);    // G7 (12,11)
        const int pb = swz(t);
        #pragma unroll
        for (int r = 0; r < 16; ++r) st[pb ^ prc<13,12,11,10>(r)] = v[r];
    }
    __syncthreads();

    // ---- P2: regs {9,8,7,6}; lanes t0-4->0-4, t5->10; waves t6->5, t7-9->11-13 ----
    {
        const int tb = (t & 31) | ((t & 32) << 5) | ((t & 64) >> 1) | ((t & 0x380) << 4);
        const int pb = swz(tb);
        #pragma unroll
        for (int r = 0; r < 16; ++r) v[r] = st[pb ^ prc<9,8,7,6>(r)];
        gate4pk<3,2>(v, F + 2*16);    // (9,8)
        gate4pk<1,0>(v, F + 3*16);    // (7,6)
        gate4pk<2,1>(v, G + 9*16);    // G9 (8,7)
        xchg_halfwave(v);             // reg bit0 (state 6) <-> t5 (state 10)
        gate4pk<0,3>(v, G + 8*16);    // G8 (10,9): 10@r0, 9@r3
        // write: regs r0->10, r1->7, r2->8, r3->9; t5->6
        const int tbw = (t & 31) | ((t & 32) << 1) | ((t & 64) >> 1) | ((t & 0x380) << 4);
        const int pw = swz(tbw);
        #pragma unroll
        for (int r = 0; r < 16; ++r) st[pw ^ prc<9,8,7,10>(r)] = v[r];
    }
    __syncthreads();

    // ---- P3: regs {5,4,3,2}; t0,t1->0,1; t2-4->7,8,9; t5->6; t6-9->10-13 ----
    {
        const int tb = (t & 3) | ((t & 0x1C) << 5) | ((t & 32) << 1) | ((t & 0x3C0) << 4);
        const int pb = swz(tb);
        #pragma unroll
        for (int r = 0; r < 16; ++r) v[r] = st[pb ^ prc<5,4,3,2>(r)];
        gate4pk<3,2>(v, F + 4*16);    // (5,4)
        gate4pk<1,0>(v, F + 5*16);    // (3,2)
        gate4pk<2,1>(v, G + 11*16);   // G11 (4,3)
        xchg_halfwave(v);             // reg bit0 (state 2) <-> t5 (state 6)
        gate4pk<0,3>(v, G + 10*16);   // G10 (6,5): 6@r0, 5@r3
        // write: regs r0->6, r1->3, r2->4, r3->5; t5->2  (waves stay 10..13)
        const int tbw = (t & 3) | ((t & 0x1C) << 5) | ((t & 32) >> 3) | ((t & 0x3C0) << 4);
        const int pw = swz(tbw);
        #pragma unroll
        for (int r = 0; r < 16; ++r) st[pw ^ prc<5,4,3,6>(r)] = v[r];
    }
    // No barrier: P4 reads only this wave's own writes (wave bits 10..13 fixed);
    // same-wave LDS ops are processed in order. Fence the compiler only.
    asm volatile("" ::: "memory");

    // ---- P4: regs {3,2,1,0}; t0-5 -> state 4..9; t6-9 -> 10..13 ----
    {
        const int pb = swz(t << 4);
        #pragma unroll
        for (int r = 0; r < 16; ++r) v[r] = st[pb ^ prc<3,2,1,0>(r)];
        gate4pk<1,0>(v, F + 6*16);    // (1,0)
        gate4pk<2,1>(v, G + 12*16);   // G12 (2,1)
    }

    // ---- epilogue: per-thread sums; reg bit j == state bit j ----
    float S = 0.f, s0 = 0.f, s1 = 0.f, s2 = 0.f, s3 = 0.f;
    #pragma unroll
    for (int r = 0; r < 16; ++r) {
        float p = v[r][0] * v[r][0] + v[r][1] * v[r][1];
        S += p;
        if (r & 1) s0 += p;
        if (r & 2) s1 += p;
        if (r & 4) s2 += p;
        if (r & 8) s3 += p;
    }
    // staged butterfly: total T + difference channels for lane bits (state 4..9)
    float d[6];
    float cur = S;
    #pragma unroll
    for (int k = 0; k < 6; ++k) {
        float p = __shfl_xor(cur, 1 << k, 64);
        d[k] = cur - p;            // lane0 sign is correct (+ for bit=0)
        cur += p;
        #pragma unroll
        for (int j = 0; j < k; ++j) d[j] += __shfl_xor(d[j], 1 << k, 64);
    }
    #pragma unroll
    for (int k = 0; k < 6; ++k) {
        s0 += __shfl_xor(s0, 1 << k, 64);
        s1 += __shfl_xor(s1, 1 << k, 64);
        s2 += __shfl_xor(s2, 1 << k, 64);
        s3 += __shfl_xor(s3, 1 << k, 64);
    }
    __syncthreads();               // all state reads done; reuse st as scratch
    float* part = (float*)st;      // [16 waves][12]: T, d0..d5, s0..s3
    const int lane = t & 63, wv = t >> 6;
    if (lane == 0) {
        part[wv*12 + 0] = cur;
        #pragma unroll
        for (int k = 0; k < 6; ++k) part[wv*12 + 1 + k] = d[k];
        part[wv*12 + 7] = s0; part[wv*12 + 8] = s1;
        part[wv*12 + 9] = s2; part[wv*12 + 10] = s3;
    }
    __syncthreads();
    if (t < WIRES) {
        const int bb = 13 - t;
        float acc = 0.f;
        if (bb <= 3) {
            #pragma unroll
            for (int w = 0; w < 16; ++w) acc += part[w*12] - 2.f * part[w*12 + 7 + bb];
        } else if (bb <= 9) {
            #pragma unroll
            for (int w = 0; w < 16; ++w) acc += part[w*12 + 1 + (bb - 4)];
        } else {
            #pragma unroll
            for (int w = 0; w < 16; ++w)
                acc += ((w >> (bb - 10)) & 1) ? -part[w*12] : part[w*12];
        }
        out[b * WIRES + t] = acc;
    }
}

// ============ fallback (ws too small): 5-phase, ENC fused in-block via LDS ============
__global__ __launch_bounds__(NTH) void sim_fb(const float* __restrict__ inputs,
                                              const float2* __restrict__ gates,
                                              float* __restrict__ out) {
    __shared__ float2 st[NSTATE];
    __shared__ float2 Fsh[7 * 16];
    const int b = blockIdx.x;
    const int t = threadIdx.x;
    const float* inp = inputs + b * WIRES;

    if (t < 7) {
        const int j = t;
        float c1, s1, c2, s2;
        sincosf(inp[2*j]     * 0.5f, &s1, &c1);
        sincosf(inp[2*j + 1] * 0.5f, &s2, &c2);
        float E[16] = { c1*c2, -c1*s2, -s1*c2,  s1*s2,
                        c1*s2,  c1*c2, -s1*s2, -s1*c2,
                        s1*c2, -s1*s2,  c1*c2, -c1*s2,
                        s1*s2,  s1*c2,  c1*s2,  c1*c2 };
        const float2* Gj = gates + j * 16;
        #pragma unroll
        for (int r = 0; r < 4; ++r)
            #pragma unroll
            for (int c = 0; c < 4; ++c) {
                float2 a = make_float2(0.f, 0.f);
                #pragma unroll
                for (int k = 0; k < 4; ++k) {
                    a.x += Gj[r*4+k].x * E[k*4+c];
                    a.y += Gj[r*4+k].y * E[k*4+c];
                }
                Fsh[j*16 + r*4 + c] = a;
            }
    }
    __syncthreads();

    float2 v[16];
    {
        #pragma unroll
        for (int r = 0; r < 16; ++r) v[r] = make_float2(0.f, 0.f);
        if (t == 0) v[0].x = 1.f;
        gate4<3,2>(v, Fsh + 0*16);
        gate4<1,0>(v, Fsh + 1*16);
        gate4<2,1>(v, gates + 7*16);
        const int pb = swz(t);
        #pragma unroll
        for (int r = 0; r < 16; ++r) st[pb ^ prc<13,12,11,10>(r)] = v[r];
    }
    __syncthreads();
    {
        const int tb = (t & 63) | ((t & 0x3C0) << 4);
        const int pb = swz(tb);
        #pragma unroll
        for (int r = 0; r < 16; ++r) v[r] = st[pb ^ prc<9,8,7,6>(r)];
        gate4<3,2>(v, Fsh + 2*16);
        gate4<1,0>(v, Fsh + 3*16);
        gate4<2,1>(v, gates + 9*16);
        #pragma unroll
        for (int r = 0; r < 16; ++r) st[pb ^ prc<9,8,7,6>(r)] = v[r];
    }
    __syncthreads();
    {
        const int tb = (t & 3) | ((t & 0x3FC) << 4);
        const int pb = swz(tb);
        #pragma unroll
        for (int r = 0; r < 16; ++r) v[r] = st[pb ^ prc<5,4,3,2>(r)];
        gate4<3,2>(v, Fsh + 4*16);
        gate4<1,0>(v, Fsh + 5*16);
        gate4<2,1>(v, gates + 11*16);
        #pragma unroll
        for (int r = 0; r < 16; ++r) st[pb ^ prc<5,4,3,2>(r)] = v[r];
    }
    __syncthreads();
    {
        const int tb = t << 4;
        const int pb = swz(tb);
        #pragma unroll
        for (int r = 0; r < 16; ++r) v[r] = st[pb ^ prc<3,2,1,0>(r)];
        gate4<1,0>(v, Fsh + 6*16);
        gate4<2,1>(v, gates + 12*16);
        #pragma unroll
        for (int r = 0; r < 16; ++r) st[pb ^ prc<3,2,1,0>(r)] = v[r];
    }
    __syncthreads();
    int tb5;
    {
        tb5 = (t & 31) | ((t & 0x60) << 2) | ((t & 0x380) << 4);
        const int pb = swz(tb5);
        #pragma unroll
        for (int r = 0; r < 16; ++r) v[r] = st[pb ^ prc<10,9,6,5>(r)];
        gate4<3,2>(v, gates + 8*16);
        gate4<1,0>(v, gates + 10*16);
    }
    float S = 0.f, s5 = 0.f, s6 = 0.f, s9 = 0.f, s10 = 0.f;
    #pragma unroll
    for (int r = 0; r < 16; ++r) {
        float p = v[r].x * v[r].x + v[r].y * v[r].y;
        S += p;
        if (r & 1) s5  += p;
        if (r & 2) s6  += p;
        if (r & 4) s9  += p;
        if (r & 8) s10 += p;
    }
    float zq[WIRES];
    #pragma unroll
    for (int q = 0; q < WIRES; ++q) {
        const int bb = 13 - q;
        if      (bb == 10) zq[q] = S - 2.f * s10;
        else if (bb == 9)  zq[q] = S - 2.f * s9;
        else if (bb == 6)  zq[q] = S - 2.f * s6;
        else if (bb == 5)  zq[q] = S - 2.f * s5;
        else               zq[q] = ((tb5 >> bb) & 1) ? -S : S;
    }
    #pragma unroll
    for (int q = 0; q < WIRES; ++q) {
        #pragma unroll
        for (int off = 32; off >= 1; off >>= 1)
            zq[q] += __shfl_xor(zq[q], off, 64);
    }
    __syncthreads();
    float* part = (float*)Fsh;
    const int lane = t & 63, wv = t >> 6;
    if (lane == 0) {
        #pragma unroll
        for (int q = 0; q < WIRES; ++q) part[wv * WIRES + q] = zq[q];
    }
    __syncthreads();
    if (t < WIRES) {
        float s = 0.f;
        #pragma unroll
        for (int w = 0; w < NTH / 64; ++w) s += part[w * WIRES + t];
        out[b * WIRES + t] = s;
    }
}

extern "C" void kernel_launch(void* const* d_in, const int* in_sizes, int n_in,
                              void* d_out, int out_size, void* d_ws, size_t ws_size,
                              hipStream_t stream) {
    const float* inputs = (const float*)d_in[0];
    const float* params = (const float*)d_in[1];
    float* out = (float*)d_out;
    float2* ws = (float2*)d_ws;

    const int batch = in_sizes[0] / WIRES;
    const size_t needed = (F_OFF + (size_t)batch * 7 * 16) * sizeof(float2);

    gate_prep<<<1, 64, 0, stream>>>(params, ws);
    if (ws_size >= needed) {
        enc_prep<<<(batch * 7 + 255) / 256, 256, 0, stream>>>(inputs, ws, batch);
        sim<<<batch, NTH, 0, stream>>>((const v2f*)ws, out);
    } else {
        sim_fb<<<batch, NTH, 0, stream>>>(inputs, ws, out);
    }
}

// Round 8
// 83.698 us; speedup vs baseline: 2.0004x; 1.0863x over previous
//
#include <hip/hip_runtime.h>

#define WIRES 14
#define NSTATE (1 << WIRES)   // 16384
#define NTH 1024
#define NVB 13                // variational blocks
#define F_OFF (NVB * 16)      // float2 offset of per-sample fused-ENC region in ws

typedef __attribute__((ext_vector_type(16))) float f16v;
typedef __attribute__((ext_vector_type(2)))  float v2f;

__device__ __forceinline__ float2 cmul(float2 a, float2 b) {
    return make_float2(a.x * b.x - a.y * b.y, a.x * b.y + a.y * b.x);
}

// ============ kernel 1: fuse each 10-gate variational block into one 4x4 ============
__global__ void gate_prep(const float* __restrict__ params, float2* __restrict__ G) {
    int k = threadIdx.x;
    if (k >= NVB) return;
    const float* p = params + k * 10;

    float2 U1[4], U2[4], U3[4], U4[4];
    auto rzrx = [](float trx, float trz, float2* U) {
        float cx, sx, cz, sz;
        sincosf(trx * 0.5f, &sx, &cx);
        sincosf(trz * 0.5f, &sz, &cz);
        float2 e0 = make_float2(cz, -sz);   // e^{-i h}
        float2 e1 = make_float2(cz,  sz);   // e^{+i h}
        U[0] = cmul(e0, make_float2(cx, 0.f));
        U[1] = cmul(e0, make_float2(0.f, -sx));
        U[2] = cmul(e1, make_float2(0.f, -sx));
        U[3] = cmul(e1, make_float2(cx, 0.f));
    };
    rzrx(p[0], p[1], U1);   // q1, first
    rzrx(p[2], p[3], U2);   // q2, first
    rzrx(p[5], p[6], U3);   // q1, second
    rzrx(p[7], p[8], U4);   // q2, second

    float2 K12[16], K34[16];
    for (int r1 = 0; r1 < 2; ++r1)
        for (int r2 = 0; r2 < 2; ++r2)
            for (int c1 = 0; c1 < 2; ++c1)
                for (int c2 = 0; c2 < 2; ++c2) {
                    int idx = (r1 * 2 + r2) * 4 + (c1 * 2 + c2);
                    K12[idx] = cmul(U1[r1 * 2 + c1], U2[r2 * 2 + c2]);
                    K34[idx] = cmul(U3[r1 * 2 + c1], U4[r2 * 2 + c2]);
                }

    float2 C1[16], C2[16];
    for (int i = 0; i < 16; ++i) { C1[i] = make_float2(0.f, 0.f); C2[i] = make_float2(0.f, 0.f); }
    {
        float c, s;
        sincosf(p[4] * 0.5f, &s, &c);        // CRY ctrl=q1(high local bit), tgt=q2
        C1[0]  = make_float2(1.f, 0.f); C1[5]  = make_float2(1.f, 0.f);
        C1[10] = make_float2(c, 0.f);   C1[11] = make_float2(-s, 0.f);
        C1[14] = make_float2(s, 0.f);   C1[15] = make_float2(c, 0.f);
        sincosf(p[9] * 0.5f, &s, &c);        // CRY ctrl=q2(low local bit), tgt=q1
        C2[0]  = make_float2(1.f, 0.f); C2[10] = make_float2(1.f, 0.f);
        C2[5]  = make_float2(c, 0.f);   C2[7]  = make_float2(-s, 0.f);
        C2[13] = make_float2(s, 0.f);   C2[15] = make_float2(c, 0.f);
    }

    float2 T1[16], T2[16], Gk[16];
    for (int r = 0; r < 4; ++r)
        for (int c = 0; c < 4; ++c) {
            float2 a = make_float2(0.f, 0.f);
            for (int j = 0; j < 4; ++j) { float2 m = cmul(C1[r*4+j], K12[j*4+c]); a.x += m.x; a.y += m.y; }
            T1[r*4+c] = a;
        }
    for (int r = 0; r < 4; ++r)
        for (int c = 0; c < 4; ++c) {
            float2 a = make_float2(0.f, 0.f);
            for (int j = 0; j < 4; ++j) { float2 m = cmul(K34[r*4+j], T1[j*4+c]); a.x += m.x; a.y += m.y; }
            T2[r*4+c] = a;
        }
    for (int r = 0; r < 4; ++r)
        for (int c = 0; c < 4; ++c) {
            float2 a = make_float2(0.f, 0.f);
            for (int j = 0; j < 4; ++j) { float2 m = cmul(C2[r*4+j], T2[j*4+c]); a.x += m.x; a.y += m.y; }
            Gk[r*4+c] = a;
        }
    for (int i = 0; i < 16; ++i) G[k * 16 + i] = Gk[i];
}

// ============ kernel 1b: per-sample fuse ENC pair j into layer-1 block: F = G_j * E ============
__global__ void enc_prep(const float* __restrict__ inputs, float2* __restrict__ ws, int batch) {
    int idx = blockIdx.x * blockDim.x + threadIdx.x;
    if (idx >= batch * 7) return;
    const int b = idx / 7, j = idx % 7;
    float c1, s1, c2, s2;
    sincosf(inputs[b * WIRES + 2*j]     * 0.5f, &s1, &c1);
    sincosf(inputs[b * WIRES + 2*j + 1] * 0.5f, &s2, &c2);
    float E[16] = { c1*c2, -c1*s2, -s1*c2,  s1*s2,
                    c1*s2,  c1*c2, -s1*s2, -s1*c2,
                    s1*c2, -s1*s2,  c1*c2, -c1*s2,
                    s1*s2,  s1*c2,  c1*s2,  c1*c2 };
    const float2* Gj = ws + j * 16;
    float2* F = ws + F_OFF + (size_t)(b * 7 + j) * 16;
    #pragma unroll
    for (int r = 0; r < 4; ++r)
        #pragma unroll
        for (int c = 0; c < 4; ++c) {
            float2 a = make_float2(0.f, 0.f);
            #pragma unroll
            for (int k = 0; k < 4; ++k) {
                a.x += Gj[r*4+k].x * E[k*4+c];
                a.y += Gj[r*4+k].y * E[k*4+c];
            }
            F[r*4+c] = a;
        }
}

// ============ sim kernel helpers ============

// GF(2)-linear LDS swizzle on a 4-byte word index (folds bits 5..9 into 0..4).
// Bank = bits 0..4 of the swizzled index; every phase's lane->bank map below
// has XOR-kernel dim <= 1 -> exactly 2 lanes/bank (free on 32-bank LDS).
__device__ __forceinline__ int swz5(int i) { return i ^ ((i >> 5) & 31); }

// compile-time: scatter r's 4 bits to global state-bit positions, then swizzle
template<int B3,int B2,int B1,int B0>
constexpr int prc5(int r) {
    int s = ((r&1)?(1<<B0):0) | ((r&2)?(1<<B1):0) | ((r&4)?(1<<B2):0) | ((r&8)?(1<<B3):0);
    return s ^ ((s >> 5) & 31);
}

// f32 pair <-> packed f16x2 (state storage format in LDS)
__device__ __forceinline__ unsigned pkf16(v2f v) {
    unsigned r;
    asm("v_cvt_pkrtz_f16_f32 %0, %1, %2" : "=v"(r) : "v"(v[0]), "v"(v[1]));
    return r;
}
__device__ __forceinline__ v2f upkf16(unsigned u) {
    float lo, hi; unsigned h;
    asm("v_cvt_f32_f16 %0, %1" : "=v"(lo) : "v"(u));
    asm("v_lshrrev_b32 %0, 16, %1" : "=v"(h) : "v"(u));
    asm("v_cvt_f32_f16 %0, %1" : "=v"(hi) : "v"(h));
    return (v2f){lo, hi};
}

// scalar-load 32 floats (one 4x4 complex gate) from a wave-uniform global
// address into SGPRs: zero VGPR cost for gate coefficients.
__device__ __forceinline__ void sload32(const float2* p, f16v& lo, f16v& hi) {
    asm volatile("s_load_dwordx16 %0, %2, 0x0\n\t"
                 "s_load_dwordx16 %1, %2, 0x40\n\t"
                 "s_waitcnt lgkmcnt(0)"
                 : "=&s"(lo), "=&s"(hi)
                 : "s"(p));
}

// ---- packed complex arithmetic: coeff (a,b) in an SGPR pair; op_sel/neg
// modifiers implement w += (a+ib)*v in TWO v_pk instructions.
__device__ __forceinline__ void cmul_pk(v2f& w, v2f ab, v2f v) {
    asm("v_pk_mul_f32 %0, %1, %2 op_sel:[0,0] op_sel_hi:[0,1]\n\t"
        "v_pk_fma_f32 %0, %1, %2, %0 op_sel:[1,1,0] op_sel_hi:[1,0,1] neg_lo:[1,0,0]"
        : "=&v"(w) : "s"(ab), "v"(v));
}
__device__ __forceinline__ void cfma_pk(v2f& w, v2f ab, v2f v) {
    asm("v_pk_fma_f32 %0, %1, %2, %0 op_sel:[0,0,0] op_sel_hi:[0,1,1]\n\t"
        "v_pk_fma_f32 %0, %1, %2, %0 op_sel:[1,1,0] op_sel_hi:[1,0,1] neg_lo:[1,0,0]"
        : "+v"(w) : "s"(ab), "v"(v));
}

// complex 4x4 gate on local register-bit pair (PH = reg bit of the HIGH state
// bit, PL = reg bit of the LOW state bit); coeffs from SGPRs, packed-f32 math.
template<int PH,int PL>
__device__ __forceinline__ void gate4pk(v2f v[16], const float2* __restrict__ gp) {
    f16v lo, hi;
    sload32(gp, lo, hi);
    constexpr int mask = (1<<PH) | (1<<PL);
    #pragma unroll
    for (int base = 0; base < 16; ++base) {
        if (base & mask) continue;
        const int i0 = base, i1 = base | (1<<PL), i2 = base | (1<<PH), i3 = base | mask;
        v2f v0 = v[i0], v1 = v[i1], v2 = v[i2], v3 = v[i3];
        v2f w0, w1, w2, w3;
#define CC(V, J) ((v2f){V[2*(J)], V[2*(J)+1]})
        cmul_pk(w0, CC(lo,0), v0); cfma_pk(w0, CC(lo,1), v1); cfma_pk(w0, CC(lo,2), v2); cfma_pk(w0, CC(lo,3), v3);
        cmul_pk(w1, CC(lo,4), v0); cfma_pk(w1, CC(lo,5), v1); cfma_pk(w1, CC(lo,6), v2); cfma_pk(w1, CC(lo,7), v3);
        cmul_pk(w2, CC(hi,0), v0); cfma_pk(w2, CC(hi,1), v1); cfma_pk(w2, CC(hi,2), v2); cfma_pk(w2, CC(hi,3), v3);
        cmul_pk(w3, CC(hi,4), v0); cfma_pk(w3, CC(hi,5), v1); cfma_pk(w3, CC(hi,6), v2); cfma_pk(w3, CC(hi,7), v3);
#undef CC
        v[i0] = w0; v[i1] = w1; v[i2] = w2; v[i3] = w3;
    }
}

// 1-bit exchange: reg bit 0 <-> lane bit 5 (half-wave) via v_permlane32_swap_b32.
__device__ __forceinline__ void xchg_halfwave(v2f v[16]) {
    #pragma unroll
    for (int r = 0; r < 16; r += 2) {
        asm volatile("v_permlane32_swap_b32 %0, %1" : "+v"(v[r][0]), "+v"(v[r+1][0]));
        asm volatile("v_permlane32_swap_b32 %0, %1" : "+v"(v[r][1]), "+v"(v[r+1][1]));
    }
}

// plain-VGPR scalar variant (works with LDS pointers) for the fallback kernel
template<int PH,int PL>
__device__ __forceinline__ void gate4(float2 v[16], const float2* __restrict__ g) {
    constexpr int mask = (1<<PH) | (1<<PL);
    #pragma unroll
    for (int base = 0; base < 16; ++base) {
        if (base & mask) continue;
        const int i0 = base, i1 = base | (1<<PL), i2 = base | (1<<PH), i3 = base | mask;
        float2 v0 = v[i0], v1 = v[i1], v2 = v[i2], v3 = v[i3];
        float2 w0, w1, w2, w3;
#define CROW(R, W)                                                                     \
        W.x = g[4*R+0].x*v0.x - g[4*R+0].y*v0.y + g[4*R+1].x*v1.x - g[4*R+1].y*v1.y    \
            + g[4*R+2].x*v2.x - g[4*R+2].y*v2.y + g[4*R+3].x*v3.x - g[4*R+3].y*v3.y;   \
        W.y = g[4*R+0].x*v0.y + g[4*R+0].y*v0.x + g[4*R+1].x*v1.y + g[4*R+1].y*v1.x    \
            + g[4*R+2].x*v2.y + g[4*R+2].y*v2.x + g[4*R+3].x*v3.y + g[4*R+3].y*v3.x;
        CROW(0, w0) CROW(1, w1) CROW(2, w2) CROW(3, w3)
#undef CROW
        v[i0] = w0; v[i1] = w1; v[i2] = w2; v[i3] = w3;
    }
}

// ============ kernel 2: 4-phase register-blocked simulation, f16x2 LDS state ============
// State lives in LDS as packed f16x2 (64 KiB -> 2 blocks/CU, 32 waves/CU);
// registers stay f32, so the state is only rounded at 3 phase boundaries.
// Wave bits of P3-write == P4-read ({10..13}) -> that transition is barrier-free.
__global__ __launch_bounds__(NTH)
void sim(const v2f* __restrict__ ws, float* __restrict__ out) {
    __shared__ unsigned st[NSTATE];    // 64 KiB packed state
    const int b = blockIdx.x;
    const int t = threadIdx.x;
    const float2* G = (const float2*)ws;
    const float2* F = (const float2*)(ws + F_OFF) + (size_t)b * 7 * 16;

    v2f v[16];

    // ---- P1: regs r0..r3 -> state {10,11,12,13}; t0..t9 -> state 0..9 ----
    {
        #pragma unroll
        for (int r = 0; r < 16; ++r) v[r] = (v2f){0.f, 0.f};
        if (t == 0) v[0] = (v2f){1.f, 0.f};
        gate4pk<3,2>(v, F + 0*16);    // (13,12)
        gate4pk<1,0>(v, F + 1*16);    // (11,10)
        gate4pk<2,1>(v, G + 7*16);    // G7 (12,11)
        const int pb = swz5(t);
        #pragma unroll
        for (int r = 0; r < 16; ++r) st[pb ^ prc5<13,12,11,10>(r)] = pkf16(v[r]);
    }
    __syncthreads();

    // ---- P2: regs {9,8,7,6}; lanes t0-4->0-4, t5->10; waves t6->5, t7-9->11-13 ----
    {
        const int tb = (t & 31) | ((t & 32) << 5) | ((t & 64) >> 1) | ((t & 0x380) << 4);
        const int pb = swz5(tb);
        #pragma unroll
        for (int r = 0; r < 16; ++r) v[r] = upkf16(st[pb ^ prc5<9,8,7,6>(r)]);
        gate4pk<3,2>(v, F + 2*16);    // (9,8)
        gate4pk<1,0>(v, F + 3*16);    // (7,6)
        gate4pk<2,1>(v, G + 9*16);    // G9 (8,7)
        xchg_halfwave(v);             // reg bit0 (state 6) <-> t5 (state 10)
        gate4pk<0,3>(v, G + 8*16);    // G8 (10,9): 10@r0, 9@r3
        // write: regs r0->10, r1->7, r2->8, r3->9; t5->6
        const int tbw = (t & 31) | ((t & 32) << 1) | ((t & 64) >> 1) | ((t & 0x380) << 4);
        const int pw = swz5(tbw);
        #pragma unroll
        for (int r = 0; r < 16; ++r) st[pw ^ prc5<9,8,7,10>(r)] = pkf16(v[r]);
    }
    __syncthreads();

    // ---- P3: regs {5,4,3,2}; t0,t1->0,1; t2-4->7,8,9; t5->6; t6-9->10-13 ----
    {
        const int tb = (t & 3) | ((t & 0x1C) << 5) | ((t & 32) << 1) | ((t & 0x3C0) << 4);
        const int pb = swz5(tb);
        #pragma unroll
        for (int r = 0; r < 16; ++r) v[r] = upkf16(st[pb ^ prc5<5,4,3,2>(r)]);
        gate4pk<3,2>(v, F + 4*16);    // (5,4)
        gate4pk<1,0>(v, F + 5*16);    // (3,2)
        gate4pk<2,1>(v, G + 11*16);   // G11 (4,3)
        xchg_halfwave(v);             // reg bit0 (state 2) <-> t5 (state 6)
        gate4pk<0,3>(v, G + 10*16);   // G10 (6,5): 6@r0, 5@r3
        // write: regs r0->6, r1->3, r2->4, r3->5; t5->2  (waves stay 10..13)
        const int tbw = (t & 3) | ((t & 0x1C) << 5) | ((t & 32) >> 3) | ((t & 0x3C0) << 4);
        const int pw = swz5(tbw);
        #pragma unroll
        for (int r = 0; r < 16; ++r) st[pw ^ prc5<5,4,3,6>(r)] = pkf16(v[r]);
    }
    // No barrier: P4 reads only this wave's own writes (wave bits 10..13 fixed);
    // same-wave LDS ops are processed in order. Fence the compiler only.
    asm volatile("" ::: "memory");

    // ---- P4: regs {3,2,1,0}; t0-5 -> state 4..9; t6-9 -> 10..13 ----
    {
        const int pb = swz5(t << 4);
        #pragma unroll
        for (int r = 0; r < 16; ++r) v[r] = upkf16(st[pb ^ prc5<3,2,1,0>(r)]);
        gate4pk<1,0>(v, F + 6*16);    // (1,0)
        gate4pk<2,1>(v, G + 12*16);   // G12 (2,1)
    }

    // ---- epilogue: per-thread sums; reg bit j == state bit j ----
    float S = 0.f, s0 = 0.f, s1 = 0.f, s2 = 0.f, s3 = 0.f;
    #pragma unroll
    for (int r = 0; r < 16; ++r) {
        float p = v[r][0] * v[r][0] + v[r][1] * v[r][1];
        S += p;
        if (r & 1) s0 += p;
        if (r & 2) s1 += p;
        if (r & 4) s2 += p;
        if (r & 8) s3 += p;
    }
    // staged butterfly: total T + difference channels for lane bits (state 4..9)
    float d[6];
    float cur = S;
    #pragma unroll
    for (int k = 0; k < 6; ++k) {
        float p = __shfl_xor(cur, 1 << k, 64);
        d[k] = cur - p;            // lane0 sign is correct (+ for bit=0)
        cur += p;
        #pragma unroll
        for (int j = 0; j < k; ++j) d[j] += __shfl_xor(d[j], 1 << k, 64);
    }
    #pragma unroll
    for (int k = 0; k < 6; ++k) {
        s0 += __shfl_xor(s0, 1 << k, 64);
        s1 += __shfl_xor(s1, 1 << k, 64);
        s2 += __shfl_xor(s2, 1 << k, 64);
        s3 += __shfl_xor(s3, 1 << k, 64);
    }
    __syncthreads();               // all state reads done; reuse st as scratch
    float* part = (float*)st;      // [16 waves][12]: T, d0..d5, s0..s3
    const int lane = t & 63, wv = t >> 6;
    if (lane == 0) {
        part[wv*12 + 0] = cur;
        #pragma unroll
        for (int k = 0; k < 6; ++k) part[wv*12 + 1 + k] = d[k];
        part[wv*12 + 7] = s0; part[wv*12 + 8] = s1;
        part[wv*12 + 9] = s2; part[wv*12 + 10] = s3;
    }
    __syncthreads();
    if (t < WIRES) {
        const int bb = 13 - t;
        float acc = 0.f;
        if (bb <= 3) {
            #pragma unroll
            for (int w = 0; w < 16; ++w) acc += part[w*12] - 2.f * part[w*12 + 7 + bb];
        } else if (bb <= 9) {
            #pragma unroll
            for (int w = 0; w < 16; ++w) acc += part[w*12 + 1 + (bb - 4)];
        } else {
            #pragma unroll
            for (int w = 0; w < 16; ++w)
                acc += ((w >> (bb - 10)) & 1) ? -part[w*12] : part[w*12];
        }
        out[b * WIRES + t] = acc;
    }
}

// ============ fallback (ws too small): 5-phase, ENC fused in-block via LDS, f32 state ============
__device__ __forceinline__ int swz(int i) { return i ^ ((i >> 4) & 15); }
template<int B3,int B2,int B1,int B0>
constexpr int prc(int r) {
    int s = ((r&1)?(1<<B0):0) | ((r&2)?(1<<B1):0) | ((r&4)?(1<<B2):0) | ((r&8)?(1<<B3):0);
    return s ^ ((s >> 4) & 15);
}

__global__ __launch_bounds__(NTH) void sim_fb(const float* __restrict__ inputs,
                                              const float2* __restrict__ gates,
                                              float* __restrict__ out) {
    __shared__ float2 st[NSTATE];
    __shared__ float2 Fsh[7 * 16];
    const int b = blockIdx.x;
    const int t = threadIdx.x;
    const float* inp = inputs + b * WIRES;

    if (t < 7) {
        const int j = t;
        float c1, s1, c2, s2;
        sincosf(inp[2*j]     * 0.5f, &s1, &c1);
        sincosf(inp[2*j + 1] * 0.5f, &s2, &c2);
        float E[16] = { c1*c2, -c1*s2, -s1*c2,  s1*s2,
                        c1*s2,  c1*c2, -s1*s2, -s1*c2,
                        s1*c2, -s1*s2,  c1*c2, -c1*s2,
                        s1*s2,  s1*c2,  c1*s2,  c1*c2 };
        const float2* Gj = gates + j * 16;
        #pragma unroll
        for (int r = 0; r < 4; ++r)
            #pragma unroll
            for (int c = 0; c < 4; ++c) {
                float2 a = make_float2(0.f, 0.f);
                #pragma unroll
                for (int k = 0; k < 4; ++k) {
                    a.x += Gj[r*4+k].x * E[k*4+c];
                    a.y += Gj[r*4+k].y * E[k*4+c];
                }
                Fsh[j*16 + r*4 + c] = a;
            }
    }
    __syncthreads();

    float2 v[16];
    {
        #pragma unroll
        for (int r = 0; r < 16; ++r) v[r] = make_float2(0.f, 0.f);
        if (t == 0) v[0].x = 1.f;
        gate4<3,2>(v, Fsh + 0*16);
        gate4<1,0>(v, Fsh + 1*16);
        gate4<2,1>(v, gates + 7*16);
        const int pb = swz(t);
        #pragma unroll
        for (int r = 0; r < 16; ++r) st[pb ^ prc<13,12,11,10>(r)] = v[r];
    }
    __syncthreads();
    {
        const int tb = (t & 63) | ((t & 0x3C0) << 4);
        const int pb = swz(tb);
        #pragma unroll
        for (int r = 0; r < 16; ++r) v[r] = st[pb ^ prc<9,8,7,6>(r)];
        gate4<3,2>(v, Fsh + 2*16);
        gate4<1,0>(v, Fsh + 3*16);
        gate4<2,1>(v, gates + 9*16);
        #pragma unroll
        for (int r = 0; r < 16; ++r) st[pb ^ prc<9,8,7,6>(r)] = v[r];
    }
    __syncthreads();
    {
        const int tb = (t & 3) | ((t & 0x3FC) << 4);
        const int pb = swz(tb);
        #pragma unroll
        for (int r = 0; r < 16; ++r) v[r] = st[pb ^ prc<5,4,3,2>(r)];
        gate4<3,2>(v, Fsh + 4*16);
        gate4<1,0>(v, Fsh + 5*16);
        gate4<2,1>(v, gates + 11*16);
        #pragma unroll
        for (int r = 0; r < 16; ++r) st[pb ^ prc<5,4,3,2>(r)] = v[r];
    }
    __syncthreads();
    {
        const int tb = t << 4;
        const int pb = swz(tb);
        #pragma unroll
        for (int r = 0; r < 16; ++r) v[r] = st[pb ^ prc<3,2,1,0>(r)];
        gate4<1,0>(v, Fsh + 6*16);
        gate4<2,1>(v, gates + 12*16);
        #pragma unroll
        for (int r = 0; r < 16; ++r) st[pb ^ prc<3,2,1,0>(r)] = v[r];
    }
    __syncthreads();
    int tb5;
    {
        tb5 = (t & 31) | ((t & 0x60) << 2) | ((t & 0x380) << 4);
        const int pb = swz(tb5);
        #pragma unroll
        for (int r = 0; r < 16; ++r) v[r] = st[pb ^ prc<10,9,6,5>(r)];
        gate4<3,2>(v, gates + 8*16);
        gate4<1,0>(v, gates + 10*16);
    }
    float S = 0.f, s5 = 0.f, s6 = 0.f, s9 = 0.f, s10 = 0.f;
    #pragma unroll
    for (int r = 0; r < 16; ++r) {
        float p = v[r].x * v[r].x + v[r].y * v[r].y;
        S += p;
        if (r & 1) s5  += p;
        if (r & 2) s6  += p;
        if (r & 4) s9  += p;
        if (r & 8) s10 += p;
    }
    float zq[WIRES];
    #pragma unroll
    for (int q = 0; q < WIRES; ++q) {
        const int bb = 13 - q;
        if      (bb == 10) zq[q] = S - 2.f * s10;
        else if (bb == 9)  zq[q] = S - 2.f * s9;
        else if (bb == 6)  zq[q] = S - 2.f * s6;
        else if (bb == 5)  zq[q] = S - 2.f * s5;
        else               zq[q] = ((tb5 >> bb) & 1) ? -S : S;
    }
    #pragma unroll
    for (int q = 0; q < WIRES; ++q) {
        #pragma unroll
        for (int off = 32; off >= 1; off >>= 1)
            zq[q] += __shfl_xor(zq[q], off, 64);
    }
    __syncthreads();
    float* part = (float*)Fsh;
    const int lane = t & 63, wv = t >> 6;
    if (lane == 0) {
        #pragma unroll
        for (int q = 0; q < WIRES; ++q) part[wv * WIRES + q] = zq[q];
    }
    __syncthreads();
    if (t < WIRES) {
        float s = 0.f;
        #pragma unroll
        for (int w = 0; w < NTH / 64; ++w) s += part[w * WIRES + t];
        out[b * WIRES + t] = s;
    }
}

extern "C" void kernel_launch(void* const* d_in, const int* in_sizes, int n_in,
                              void* d_out, int out_size, void* d_ws, size_t ws_size,
                              hipStream_t stream) {
    const float* inputs = (const float*)d_in[0];
    const float* params = (const float*)d_in[1];
    float* out = (float*)d_out;
    float2* ws = (float2*)d_ws;

    const int batch = in_sizes[0] / WIRES;
    const size_t needed = (F_OFF + (size_t)batch * 7 * 16) * sizeof(float2);

    gate_prep<<<1, 64, 0, stream>>>(params, ws);
    if (ws_size >= needed) {
        enc_prep<<<(batch * 7 + 255) / 256, 256, 0, stream>>>(inputs, ws, batch);
        sim<<<batch, NTH, 0, stream>>>((const v2f*)ws, out);
    } else {
        sim_fb<<<batch, NTH, 0, stream>>>(inputs, ws, out);
    }
}

// Round 9
// 78.629 us; speedup vs baseline: 2.1293x; 1.0645x over previous
//
#include <hip/hip_runtime.h>

#define WIRES 14
#define NSTATE (1 << WIRES)   // 16384
#define NTH 1024
#define NVB 13                // variational blocks

// ws layout (dword units):
//   [0, 416)   : G in f32 float2[13*16]  (for enc_prep + fallback)
//   [416, 624) : G packed f16x2 u32[13*16]
//   [624, ...) : F packed f16x2 u32[batch*7*16]
#define G16_OFF 416
#define F16_OFF 624

typedef __attribute__((ext_vector_type(16))) unsigned u16x;
typedef __attribute__((ext_vector_type(2)))  float v2f;

__device__ __forceinline__ float2 cmul(float2 a, float2 b) {
    return make_float2(a.x * b.x - a.y * b.y, a.x * b.y + a.y * b.x);
}

// f32 pair -> packed f16x2 (RTZ)
__device__ __forceinline__ unsigned packh(float x, float y) {
    unsigned r;
    asm("v_cvt_pkrtz_f16_f32 %0, %1, %2" : "=v"(r) : "v"(x), "v"(y));
    return r;
}
// packed f16x2 -> f32 pair
__device__ __forceinline__ v2f upkf16(unsigned u) {
    float lo, hi; unsigned h;
    asm("v_cvt_f32_f16 %0, %1" : "=v"(lo) : "v"(u));
    asm("v_lshrrev_b32 %0, 16, %1" : "=v"(h) : "v"(u));
    asm("v_cvt_f32_f16 %0, %1" : "=v"(hi) : "v"(h));
    return (v2f){lo, hi};
}

// ============ kernel 1: fuse each 10-gate variational block into one 4x4 ============
__global__ void gate_prep(const float* __restrict__ params, float2* __restrict__ G32,
                          unsigned* __restrict__ G16) {
    int k = threadIdx.x;
    if (k >= NVB) return;
    const float* p = params + k * 10;

    float2 U1[4], U2[4], U3[4], U4[4];
    auto rzrx = [](float trx, float trz, float2* U) {
        float cx, sx, cz, sz;
        sincosf(trx * 0.5f, &sx, &cx);
        sincosf(trz * 0.5f, &sz, &cz);
        float2 e0 = make_float2(cz, -sz);   // e^{-i h}
        float2 e1 = make_float2(cz,  sz);   // e^{+i h}
        U[0] = cmul(e0, make_float2(cx, 0.f));
        U[1] = cmul(e0, make_float2(0.f, -sx));
        U[2] = cmul(e1, make_float2(0.f, -sx));
        U[3] = cmul(e1, make_float2(cx, 0.f));
    };
    rzrx(p[0], p[1], U1);   // q1, first
    rzrx(p[2], p[3], U2);   // q2, first
    rzrx(p[5], p[6], U3);   // q1, second
    rzrx(p[7], p[8], U4);   // q2, second

    float2 K12[16], K34[16];
    for (int r1 = 0; r1 < 2; ++r1)
        for (int r2 = 0; r2 < 2; ++r2)
            for (int c1 = 0; c1 < 2; ++c1)
                for (int c2 = 0; c2 < 2; ++c2) {
                    int idx = (r1 * 2 + r2) * 4 + (c1 * 2 + c2);
                    K12[idx] = cmul(U1[r1 * 2 + c1], U2[r2 * 2 + c2]);
                    K34[idx] = cmul(U3[r1 * 2 + c1], U4[r2 * 2 + c2]);
                }

    float2 C1[16], C2[16];
    for (int i = 0; i < 16; ++i) { C1[i] = make_float2(0.f, 0.f); C2[i] = make_float2(0.f, 0.f); }
    {
        float c, s;
        sincosf(p[4] * 0.5f, &s, &c);        // CRY ctrl=q1(high local bit), tgt=q2
        C1[0]  = make_float2(1.f, 0.f); C1[5]  = make_float2(1.f, 0.f);
        C1[10] = make_float2(c, 0.f);   C1[11] = make_float2(-s, 0.f);
        C1[14] = make_float2(s, 0.f);   C1[15] = make_float2(c, 0.f);
        sincosf(p[9] * 0.5f, &s, &c);        // CRY ctrl=q2(low local bit), tgt=q1
        C2[0]  = make_float2(1.f, 0.f); C2[10] = make_float2(1.f, 0.f);
        C2[5]  = make_float2(c, 0.f);   C2[7]  = make_float2(-s, 0.f);
        C2[13] = make_float2(s, 0.f);   C2[15] = make_float2(c, 0.f);
    }

    float2 T1[16], T2[16], Gk[16];
    for (int r = 0; r < 4; ++r)
        for (int c = 0; c < 4; ++c) {
            float2 a = make_float2(0.f, 0.f);
            for (int j = 0; j < 4; ++j) { float2 m = cmul(C1[r*4+j], K12[j*4+c]); a.x += m.x; a.y += m.y; }
            T1[r*4+c] = a;
        }
    for (int r = 0; r < 4; ++r)
        for (int c = 0; c < 4; ++c) {
            float2 a = make_float2(0.f, 0.f);
            for (int j = 0; j < 4; ++j) { float2 m = cmul(K34[r*4+j], T1[j*4+c]); a.x += m.x; a.y += m.y; }
            T2[r*4+c] = a;
        }
    for (int r = 0; r < 4; ++r)
        for (int c = 0; c < 4; ++c) {
            float2 a = make_float2(0.f, 0.f);
            for (int j = 0; j < 4; ++j) { float2 m = cmul(C2[r*4+j], T2[j*4+c]); a.x += m.x; a.y += m.y; }
            Gk[r*4+c] = a;
        }
    for (int i = 0; i < 16; ++i) {
        G32[k * 16 + i] = Gk[i];
        G16[k * 16 + i] = packh(Gk[i].x, Gk[i].y);
    }
}

// ============ kernel 1b: per-sample fuse ENC pair j into layer-1 block: F = G_j * E ============
__global__ void enc_prep(const float* __restrict__ inputs, const float2* __restrict__ G32,
                         unsigned* __restrict__ F16, int batch) {
    int idx = blockIdx.x * blockDim.x + threadIdx.x;
    if (idx >= batch * 7) return;
    const int b = idx / 7, j = idx % 7;
    float c1, s1, c2, s2;
    sincosf(inputs[b * WIRES + 2*j]     * 0.5f, &s1, &c1);
    sincosf(inputs[b * WIRES + 2*j + 1] * 0.5f, &s2, &c2);
    float E[16] = { c1*c2, -c1*s2, -s1*c2,  s1*s2,
                    c1*s2,  c1*c2, -s1*s2, -s1*c2,
                    s1*c2, -s1*s2,  c1*c2, -c1*s2,
                    s1*s2,  s1*c2,  c1*s2,  c1*c2 };
    const float2* Gj = G32 + j * 16;
    unsigned* F = F16 + (size_t)(b * 7 + j) * 16;
    #pragma unroll
    for (int r = 0; r < 4; ++r)
        #pragma unroll
        for (int c = 0; c < 4; ++c) {
            float2 a = make_float2(0.f, 0.f);
            #pragma unroll
            for (int k = 0; k < 4; ++k) {
                a.x += Gj[r*4+k].x * E[k*4+c];
                a.y += Gj[r*4+k].y * E[k*4+c];
            }
            F[r*4+c] = packh(a.x, a.y);
        }
}

// ============ sim kernel helpers ============

// GF(2)-linear LDS swizzle on a 4-byte word index (folds bits 5..9 into 0..4).
__device__ __forceinline__ int swz5(int i) { return i ^ ((i >> 5) & 31); }

template<int B3,int B2,int B1,int B0>
constexpr int prc5(int r) {
    int s = ((r&1)?(1<<B0):0) | ((r&2)?(1<<B1):0) | ((r&4)?(1<<B2):0) | ((r&8)?(1<<B3):0);
    return s ^ ((s >> 5) & 31);
}

// scalar-load one f16-packed 4x4 complex gate (16 dwords) into SGPRs.
__device__ __forceinline__ void sload16(const unsigned* p, u16x& g) {
    asm volatile("s_load_dwordx16 %0, %1, 0x0\n\t"
                 "s_waitcnt lgkmcnt(0)"
                 : "=&s"(g) : "s"(p));
}

// ---- packed f16 complex arithmetic: amp = (re,im) in one u32; coeff (a,b) in
// one SGPR. w += (a+ib)*v in TWO v_pk_fma_f16 (2 cyc/wave64 each):
//   lo: a*x - b*y ; hi: a*y + b*x
__device__ __forceinline__ void cmul_pkh(unsigned& w, unsigned ab, unsigned v) {
    asm("v_pk_mul_f16 %0, %1, %2 op_sel:[0,0] op_sel_hi:[0,1]\n\t"
        "v_pk_fma_f16 %0, %1, %2, %0 op_sel:[1,1,0] op_sel_hi:[1,0,1] neg_lo:[1,0,0]"
        : "=&v"(w) : "s"(ab), "v"(v));
}
__device__ __forceinline__ void cfma_pkh(unsigned& w, unsigned ab, unsigned v) {
    asm("v_pk_fma_f16 %0, %1, %2, %0 op_sel:[0,0,0] op_sel_hi:[0,1,1]\n\t"
        "v_pk_fma_f16 %0, %1, %2, %0 op_sel:[1,1,0] op_sel_hi:[1,0,1] neg_lo:[1,0,0]"
        : "+v"(w) : "s"(ab), "v"(v));
}

// complex 4x4 gate on local register-bit pair, full f16 math.
template<int PH,int PL>
__device__ __forceinline__ void gate4h(unsigned v[16], const unsigned* __restrict__ gp) {
    u16x g;
    sload16(gp, g);
    constexpr int mask = (1<<PH) | (1<<PL);
    #pragma unroll
    for (int base = 0; base < 16; ++base) {
        if (base & mask) continue;
        const int i0 = base, i1 = base | (1<<PL), i2 = base | (1<<PH), i3 = base | mask;
        unsigned v0 = v[i0], v1 = v[i1], v2 = v[i2], v3 = v[i3];
        unsigned w0, w1, w2, w3;
        cmul_pkh(w0, g[0],  v0); cfma_pkh(w0, g[1],  v1); cfma_pkh(w0, g[2],  v2); cfma_pkh(w0, g[3],  v3);
        cmul_pkh(w1, g[4],  v0); cfma_pkh(w1, g[5],  v1); cfma_pkh(w1, g[6],  v2); cfma_pkh(w1, g[7],  v3);
        cmul_pkh(w2, g[8],  v0); cfma_pkh(w2, g[9],  v1); cfma_pkh(w2, g[10], v2); cfma_pkh(w2, g[11], v3);
        cmul_pkh(w3, g[12], v0); cfma_pkh(w3, g[13], v1); cfma_pkh(w3, g[14], v2); cfma_pkh(w3, g[15], v3);
        v[i0] = w0; v[i1] = w1; v[i2] = w2; v[i3] = w3;
    }
}

// 1-bit exchange: reg bit 0 <-> lane bit 5 (half-wave), one permlane per pair.
__device__ __forceinline__ void xchg_halfwave_h(unsigned v[16]) {
    #pragma unroll
    for (int r = 0; r < 16; r += 2)
        asm volatile("v_permlane32_swap_b32 %0, %1" : "+v"(v[r]), "+v"(v[r+1]));
}

// ============ kernel 2: 4-phase register-blocked simulation, full f16 ============
// State: one u32 (f16x2) per amplitude, in registers and LDS (64 KiB -> 2
// blocks/CU). Same phase maps/swizzles/barrier structure as the verified R8
// kernel; P3->P4 is barrier-free (wave bits {10..13} fixed).
__global__ __launch_bounds__(NTH)
void sim(const unsigned* __restrict__ G16, const unsigned* __restrict__ F16all,
         float* __restrict__ out) {
    __shared__ unsigned st[NSTATE];    // 64 KiB packed state
    const int b = blockIdx.x;
    const int t = threadIdx.x;
    const unsigned* G = G16;
    const unsigned* F = F16all + (size_t)b * 7 * 16;

    unsigned v[16];

    // ---- P1: regs r0..r3 -> state {10,11,12,13}; t0..t9 -> state 0..9 ----
    {
        #pragma unroll
        for (int r = 0; r < 16; ++r) v[r] = 0u;
        if (t == 0) v[0] = 0x3C00u;   // f16 1.0 in re
        gate4h<3,2>(v, F + 0*16);     // (13,12)
        gate4h<1,0>(v, F + 1*16);     // (11,10)
        gate4h<2,1>(v, G + 7*16);     // G7 (12,11)
        const int pb = swz5(t);
        #pragma unroll
        for (int r = 0; r < 16; ++r) st[pb ^ prc5<13,12,11,10>(r)] = v[r];
    }
    __syncthreads();

    // ---- P2: regs {9,8,7,6}; lanes t0-4->0-4, t5->10; waves t6->5, t7-9->11-13 ----
    {
        const int tb = (t & 31) | ((t & 32) << 5) | ((t & 64) >> 1) | ((t & 0x380) << 4);
        const int pb = swz5(tb);
        #pragma unroll
        for (int r = 0; r < 16; ++r) v[r] = st[pb ^ prc5<9,8,7,6>(r)];
        gate4h<3,2>(v, F + 2*16);     // (9,8)
        gate4h<1,0>(v, F + 3*16);     // (7,6)
        gate4h<2,1>(v, G + 9*16);     // G9 (8,7)
        xchg_halfwave_h(v);           // reg bit0 (state 6) <-> t5 (state 10)
        gate4h<0,3>(v, G + 8*16);     // G8 (10,9): 10@r0, 9@r3
        const int tbw = (t & 31) | ((t & 32) << 1) | ((t & 64) >> 1) | ((t & 0x380) << 4);
        const int pw = swz5(tbw);
        #pragma unroll
        for (int r = 0; r < 16; ++r) st[pw ^ prc5<9,8,7,10>(r)] = v[r];
    }
    __syncthreads();

    // ---- P3: regs {5,4,3,2}; t0,t1->0,1; t2-4->7,8,9; t5->6; t6-9->10-13 ----
    {
        const int tb = (t & 3) | ((t & 0x1C) << 5) | ((t & 32) << 1) | ((t & 0x3C0) << 4);
        const int pb = swz5(tb);
        #pragma unroll
        for (int r = 0; r < 16; ++r) v[r] = st[pb ^ prc5<5,4,3,2>(r)];
        gate4h<3,2>(v, F + 4*16);     // (5,4)
        gate4h<1,0>(v, F + 5*16);     // (3,2)
        gate4h<2,1>(v, G + 11*16);    // G11 (4,3)
        xchg_halfwave_h(v);           // reg bit0 (state 2) <-> t5 (state 6)
        gate4h<0,3>(v, G + 10*16);    // G10 (6,5): 6@r0, 5@r3
        const int tbw = (t & 3) | ((t & 0x1C) << 5) | ((t & 32) >> 3) | ((t & 0x3C0) << 4);
        const int pw = swz5(tbw);
        #pragma unroll
        for (int r = 0; r < 16; ++r) st[pw ^ prc5<5,4,3,6>(r)] = v[r];
    }
    // No barrier: P4 reads only this wave's own writes (wave bits 10..13 fixed).
    asm volatile("" ::: "memory");

    // ---- P4: regs {3,2,1,0}; t0-5 -> state 4..9; t6-9 -> 10..13 ----
    {
        const int pb = swz5(t << 4);
        #pragma unroll
        for (int r = 0; r < 16; ++r) v[r] = st[pb ^ prc5<3,2,1,0>(r)];
        gate4h<1,0>(v, F + 6*16);     // (1,0)
        gate4h<2,1>(v, G + 12*16);    // G12 (2,1)
    }

    // ---- epilogue (f32): per-thread sums; reg bit j == state bit j ----
    float S = 0.f, s0 = 0.f, s1 = 0.f, s2 = 0.f, s3 = 0.f;
    #pragma unroll
    for (int r = 0; r < 16; ++r) {
        v2f a = upkf16(v[r]);
        float p = a[0] * a[0] + a[1] * a[1];
        S += p;
        if (r & 1) s0 += p;
        if (r & 2) s1 += p;
        if (r & 4) s2 += p;
        if (r & 8) s3 += p;
    }
    // staged butterfly: total T + difference channels for lane bits (state 4..9)
    float d[6];
    float cur = S;
    #pragma unroll
    for (int k = 0; k < 6; ++k) {
        float p = __shfl_xor(cur, 1 << k, 64);
        d[k] = cur - p;            // lane0 sign is correct (+ for bit=0)
        cur += p;
        #pragma unroll
        for (int j = 0; j < k; ++j) d[j] += __shfl_xor(d[j], 1 << k, 64);
    }
    #pragma unroll
    for (int k = 0; k < 6; ++k) {
        s0 += __shfl_xor(s0, 1 << k, 64);
        s1 += __shfl_xor(s1, 1 << k, 64);
        s2 += __shfl_xor(s2, 1 << k, 64);
        s3 += __shfl_xor(s3, 1 << k, 64);
    }
    __syncthreads();               // all state reads done; reuse st as scratch
    float* part = (float*)st;      // [16 waves][12]: T, d0..d5, s0..s3
    const int lane = t & 63, wv = t >> 6;
    if (lane == 0) {
        part[wv*12 + 0] = cur;
        #pragma unroll
        for (int k = 0; k < 6; ++k) part[wv*12 + 1 + k] = d[k];
        part[wv*12 + 7] = s0; part[wv*12 + 8] = s1;
        part[wv*12 + 9] = s2; part[wv*12 + 10] = s3;
    }
    __syncthreads();
    if (t < WIRES) {
        const int bb = 13 - t;
        float acc = 0.f;
        if (bb <= 3) {
            #pragma unroll
            for (int w = 0; w < 16; ++w) acc += part[w*12] - 2.f * part[w*12 + 7 + bb];
        } else if (bb <= 9) {
            #pragma unroll
            for (int w = 0; w < 16; ++w) acc += part[w*12 + 1 + (bb - 4)];
        } else {
            #pragma unroll
            for (int w = 0; w < 16; ++w)
                acc += ((w >> (bb - 10)) & 1) ? -part[w*12] : part[w*12];
        }
        out[b * WIRES + t] = acc;
    }
}

// ============ fallback (ws too small): 5-phase, f32 state, ENC fused via LDS ============
__device__ __forceinline__ int swz(int i) { return i ^ ((i >> 4) & 15); }
template<int B3,int B2,int B1,int B0>
constexpr int prc(int r) {
    int s = ((r&1)?(1<<B0):0) | ((r&2)?(1<<B1):0) | ((r&4)?(1<<B2):0) | ((r&8)?(1<<B3):0);
    return s ^ ((s >> 4) & 15);
}

template<int PH,int PL>
__device__ __forceinline__ void gate4(float2 v[16], const float2* __restrict__ g) {
    constexpr int mask = (1<<PH) | (1<<PL);
    #pragma unroll
    for (int base = 0; base < 16; ++base) {
        if (base & mask) continue;
        const int i0 = base, i1 = base | (1<<PL), i2 = base | (1<<PH), i3 = base | mask;
        float2 v0 = v[i0], v1 = v[i1], v2 = v[i2], v3 = v[i3];
        float2 w0, w1, w2, w3;
#define CROW(R, W)                                                                     \
        W.x = g[4*R+0].x*v0.x - g[4*R+0].y*v0.y + g[4*R+1].x*v1.x - g[4*R+1].y*v1.y    \
            + g[4*R+2].x*v2.x - g[4*R+2].y*v2.y + g[4*R+3].x*v3.x - g[4*R+3].y*v3.y;   \
        W.y = g[4*R+0].x*v0.y + g[4*R+0].y*v0.x + g[4*R+1].x*v1.y + g[4*R+1].y*v1.x    \
            + g[4*R+2].x*v2.y + g[4*R+2].y*v2.x + g[4*R+3].x*v3.y + g[4*R+3].y*v3.x;
        CROW(0, w0) CROW(1, w1) CROW(2, w2) CROW(3, w3)
#undef CROW
        v[i0] = w0; v[i1] = w1; v[i2] = w2; v[i3] = w3;
    }
}

__global__ __launch_bounds__(NTH) void sim_fb(const float* __restrict__ inputs,
                                              const float2* __restrict__ gates,
                                              float* __restrict__ out) {
    __shared__ float2 st[NSTATE];
    __shared__ float2 Fsh[7 * 16];
    const int b = blockIdx.x;
    const int t = threadIdx.x;
    const float* inp = inputs + b * WIRES;

    if (t < 7) {
        const int j = t;
        float c1, s1, c2, s2;
        sincosf(inp[2*j]     * 0.5f, &s1, &c1);
        sincosf(inp[2*j + 1] * 0.5f, &s2, &c2);
        float E[16] = { c1*c2, -c1*s2, -s1*c2,  s1*s2,
                        c1*s2,  c1*c2, -s1*s2, -s1*c2,
                        s1*c2, -s1*s2,  c1*c2, -c1*s2,
                        s1*s2,  s1*c2,  c1*s2,  c1*c2 };
        const float2* Gj = gates + j * 16;
        #pragma unroll
        for (int r = 0; r < 4; ++r)
            #pragma unroll
            for (int c = 0; c < 4; ++c) {
                float2 a = make_float2(0.f, 0.f);
                #pragma unroll
                for (int k = 0; k < 4; ++k) {
                    a.x += Gj[r*4+k].x * E[k*4+c];
                    a.y += Gj[r*4+k].y * E[k*4+c];
                }
                Fsh[j*16 + r*4 + c] = a;
            }
    }
    __syncthreads();

    float2 v[16];
    {
        #pragma unroll
        for (int r = 0; r < 16; ++r) v[r] = make_float2(0.f, 0.f);
        if (t == 0) v[0].x = 1.f;
        gate4<3,2>(v, Fsh + 0*16);
        gate4<1,0>(v, Fsh + 1*16);
        gate4<2,1>(v, gates + 7*16);
        const int pb = swz(t);
        #pragma unroll
        for (int r = 0; r < 16; ++r) st[pb ^ prc<13,12,11,10>(r)] = v[r];
    }
    __syncthreads();
    {
        const int tb = (t & 63) | ((t & 0x3C0) << 4);
        const int pb = swz(tb);
        #pragma unroll
        for (int r = 0; r < 16; ++r) v[r] = st[pb ^ prc<9,8,7,6>(r)];
        gate4<3,2>(v, Fsh + 2*16);
        gate4<1,0>(v, Fsh + 3*16);
        gate4<2,1>(v, gates + 9*16);
        #pragma unroll
        for (int r = 0; r < 16; ++r) st[pb ^ prc<9,8,7,6>(r)] = v[r];
    }
    __syncthreads();
    {
        const int tb = (t & 3) | ((t & 0x3FC) << 4);
        const int pb = swz(tb);
        #pragma unroll
        for (int r = 0; r < 16; ++r) v[r] = st[pb ^ prc<5,4,3,2>(r)];
        gate4<3,2>(v, Fsh + 4*16);
        gate4<1,0>(v, Fsh + 5*16);
        gate4<2,1>(v, gates + 11*16);
        #pragma unroll
        for (int r = 0; r < 16; ++r) st[pb ^ prc<5,4,3,2>(r)] = v[r];
    }
    __syncthreads();
    {
        const int tb = t << 4;
        const int pb = swz(tb);
        #pragma unroll
        for (int r = 0; r < 16; ++r) v[r] = st[pb ^ prc<3,2,1,0>(r)];
        gate4<1,0>(v, Fsh + 6*16);
        gate4<2,1>(v, gates + 12*16);
        #pragma unroll
        for (int r = 0; r < 16; ++r) st[pb ^ prc<3,2,1,0>(r)] = v[r];
    }
    __syncthreads();
    int tb5;
    {
        tb5 = (t & 31) | ((t & 0x60) << 2) | ((t & 0x380) << 4);
        const int pb = swz(tb5);
        #pragma unroll
        for (int r = 0; r < 16; ++r) v[r] = st[pb ^ prc<10,9,6,5>(r)];
        gate4<3,2>(v, gates + 8*16);
        gate4<1,0>(v, gates + 10*16);
    }
    float S = 0.f, s5 = 0.f, s6 = 0.f, s9 = 0.f, s10 = 0.f;
    #pragma unroll
    for (int r = 0; r < 16; ++r) {
        float p = v[r].x * v[r].x + v[r].y * v[r].y;
        S += p;
        if (r & 1) s5  += p;
        if (r & 2) s6  += p;
        if (r & 4) s9  += p;
        if (r & 8) s10 += p;
    }
    float zq[WIRES];
    #pragma unroll
    for (int q = 0; q < WIRES; ++q) {
        const int bb = 13 - q;
        if      (bb == 10) zq[q] = S - 2.f * s10;
        else if (bb == 9)  zq[q] = S - 2.f * s9;
        else if (bb == 6)  zq[q] = S - 2.f * s6;
        else if (bb == 5)  zq[q] = S - 2.f * s5;
        else               zq[q] = ((tb5 >> bb) & 1) ? -S : S;
    }
    #pragma unroll
    for (int q = 0; q < WIRES; ++q) {
        #pragma unroll
        for (int off = 32; off >= 1; off >>= 1)
            zq[q] += __shfl_xor(zq[q], off, 64);
    }
    __syncthreads();
    float* part = (float*)Fsh;
    const int lane = t & 63, wv = t >> 6;
    if (lane == 0) {
        #pragma unroll
        for (int q = 0; q < WIRES; ++q) part[wv * WIRES + q] = zq[q];
    }
    __syncthreads();
    if (t < WIRES) {
        float s = 0.f;
        #pragma unroll
        for (int w = 0; w < NTH / 64; ++w) s += part[w * WIRES + t];
        out[b * WIRES + t] = s;
    }
}

extern "C" void kernel_launch(void* const* d_in, const int* in_sizes, int n_in,
                              void* d_out, int out_size, void* d_ws, size_t ws_size,
                              hipStream_t stream) {
    const float* inputs = (const float*)d_in[0];
    const float* params = (const float*)d_in[1];
    float* out = (float*)d_out;
    float2* ws32 = (float2*)d_ws;
    unsigned* wsu = (unsigned*)d_ws;

    const int batch = in_sizes[0] / WIRES;
    const size_t needed = (size_t)(F16_OFF + batch * 7 * 16) * 4;

    gate_prep<<<1, 64, 0, stream>>>(params, ws32, wsu + G16_OFF);
    if (ws_size >= needed) {
        enc_prep<<<(batch * 7 + 255) / 256, 256, 0, stream>>>(inputs, ws32, wsu + F16_OFF, batch);
        sim<<<batch, NTH, 0, stream>>>(wsu + G16_OFF, wsu + F16_OFF, out);
    } else {
        sim_fb<<<batch, NTH, 0, stream>>>(inputs, ws32, out);
    }
}

// Round 10
// 15.556 us; speedup vs baseline: 10.7631x; 5.0547x over previous
//
#include <hip/hip_runtime.h>

#define WIRES 14
#define NVB 13                // variational blocks

__device__ __forceinline__ float2 cmul(float2 a, float2 b) {
    return make_float2(a.x * b.x - a.y * b.y, a.x * b.y + a.y * b.x);
}

// ============ kernel 1: fuse each 10-gate variational block into one 4x4 ============
// (verbatim from the verified full-sim pipeline; local basis (b1,b0) with
//  b1 = q1 = first qubit of the pair)
__global__ void gate_prep(const float* __restrict__ params, float2* __restrict__ G) {
    int k = threadIdx.x;
    if (k >= NVB) return;
    const float* p = params + k * 10;

    float2 U1[4], U2[4], U3[4], U4[4];
    auto rzrx = [](float trx, float trz, float2* U) {
        float cx, sx, cz, sz;
        sincosf(trx * 0.5f, &sx, &cx);
        sincosf(trz * 0.5f, &sz, &cz);
        float2 e0 = make_float2(cz, -sz);   // e^{-i h}
        float2 e1 = make_float2(cz,  sz);   // e^{+i h}
        U[0] = cmul(e0, make_float2(cx, 0.f));
        U[1] = cmul(e0, make_float2(0.f, -sx));
        U[2] = cmul(e1, make_float2(0.f, -sx));
        U[3] = cmul(e1, make_float2(cx, 0.f));
    };
    rzrx(p[0], p[1], U1);   // q1, first
    rzrx(p[2], p[3], U2);   // q2, first
    rzrx(p[5], p[6], U3);   // q1, second
    rzrx(p[7], p[8], U4);   // q2, second

    float2 K12[16], K34[16];
    for (int r1 = 0; r1 < 2; ++r1)
        for (int r2 = 0; r2 < 2; ++r2)
            for (int c1 = 0; c1 < 2; ++c1)
                for (int c2 = 0; c2 < 2; ++c2) {
                    int idx = (r1 * 2 + r2) * 4 + (c1 * 2 + c2);
                    K12[idx] = cmul(U1[r1 * 2 + c1], U2[r2 * 2 + c2]);
                    K34[idx] = cmul(U3[r1 * 2 + c1], U4[r2 * 2 + c2]);
                }

    float2 C1[16], C2[16];
    for (int i = 0; i < 16; ++i) { C1[i] = make_float2(0.f, 0.f); C2[i] = make_float2(0.f, 0.f); }
    {
        float c, s;
        sincosf(p[4] * 0.5f, &s, &c);        // CRY ctrl=q1(high local bit), tgt=q2
        C1[0]  = make_float2(1.f, 0.f); C1[5]  = make_float2(1.f, 0.f);
        C1[10] = make_float2(c, 0.f);   C1[11] = make_float2(-s, 0.f);
        C1[14] = make_float2(s, 0.f);   C1[15] = make_float2(c, 0.f);
        sincosf(p[9] * 0.5f, &s, &c);        // CRY ctrl=q2(low local bit), tgt=q1
        C2[0]  = make_float2(1.f, 0.f); C2[10] = make_float2(1.f, 0.f);
        C2[5]  = make_float2(c, 0.f);   C2[7]  = make_float2(-s, 0.f);
        C2[13] = make_float2(s, 0.f);   C2[15] = make_float2(c, 0.f);
    }

    float2 T1[16], T2[16], Gk[16];
    for (int r = 0; r < 4; ++r)
        for (int c = 0; c < 4; ++c) {
            float2 a = make_float2(0.f, 0.f);
            for (int j = 0; j < 4; ++j) { float2 m = cmul(C1[r*4+j], K12[j*4+c]); a.x += m.x; a.y += m.y; }
            T1[r*4+c] = a;
        }
    for (int r = 0; r < 4; ++r)
        for (int c = 0; c < 4; ++c) {
            float2 a = make_float2(0.f, 0.f);
            for (int j = 0; j < 4; ++j) { float2 m = cmul(K34[r*4+j], T1[j*4+c]); a.x += m.x; a.y += m.y; }
            T2[r*4+c] = a;
        }
    for (int r = 0; r < 4; ++r)
        for (int c = 0; c < 4; ++c) {
            float2 a = make_float2(0.f, 0.f);
            for (int j = 0; j < 4; ++j) { float2 m = cmul(C2[r*4+j], T2[j*4+c]); a.x += m.x; a.y += m.y; }
            Gk[r*4+c] = a;
        }
    for (int i = 0; i < 16; ++i) G[k * 16 + i] = Gk[i];
}

// ============ kernel 2: light-cone evaluation ============
// Depth-2 brick wall => <Z_q> depends on at most 4 qubits:
//   q in layer-2 pair (a,a+1), a odd: cone = {a-1,a,a+1,a+2};
//   blocks: L1 G[s] on (2s,2s+1)=(a-1,a), L1 G[s+1] on (a+1,a+2), L2 G[7+s] on (a,a+1).
//   q=0:  only G[0] on (0,1).   q=13: only G[6] on (12,13).
// 4-qubit index bits (3,2,1,0) = (q_{a-1}, q_a, q_{a+1}, q_{a+2}).
// grid.y = seg (0..7): segs 0..5 -> a=2*seg+1 (writes Z_a, Z_{a+1});
//                      seg 6 -> Z_0; seg 7 -> Z_13.
__global__ __launch_bounds__(256)
void lightcone(const float* __restrict__ inputs, const float2* __restrict__ G,
               float* __restrict__ out, int batch) {
    const int b = blockIdx.x * 256 + threadIdx.x;
    if (b >= batch) return;
    const int seg = blockIdx.y;        // uniform per block -> scalar G loads
    const float* inp = inputs + b * WIRES;

    // v = B * (RY(tp) (x) RY(tq)) |00>  — B complex 4x4, product state real
    auto ryblk = [](const float2* __restrict__ B, float tp, float tq, float2 v[4]) {
        float cp, sp, cq, sq;
        sincosf(tp * 0.5f, &sp, &cp);
        sincosf(tq * 0.5f, &sq, &cq);
        const float e0 = cp * cq, e1 = cp * sq, e2 = sp * cq, e3 = sp * sq;
        #pragma unroll
        for (int j = 0; j < 4; ++j) {
            v[j].x = B[j*4+0].x*e0 + B[j*4+1].x*e1 + B[j*4+2].x*e2 + B[j*4+3].x*e3;
            v[j].y = B[j*4+0].y*e0 + B[j*4+1].y*e1 + B[j*4+2].y*e2 + B[j*4+3].y*e3;
        }
    };

    if (seg < 6) {
        const int a = 2 * seg + 1;
        float2 v1[4], v2[4];
        ryblk(G + seg * 16,       inp[a - 1], inp[a],     v1);   // (a-1, a)
        ryblk(G + (seg + 1) * 16, inp[a + 1], inp[a + 2], v2);   // (a+1, a+2)
        const float2* W = G + (7 + seg) * 16;                    // L2 on (a, a+1)

        float za = 0.f, zb = 0.f;
        #pragma unroll
        for (int b3 = 0; b3 < 2; ++b3)
            #pragma unroll
            for (int b0 = 0; b0 < 2; ++b0) {
                // x[j], j=(b2<<1)|b1 : psi = v1[(b3<<1)|b2] * v2[(b1<<1)|b0]
                float2 x[4], y[4];
                #pragma unroll
                for (int j = 0; j < 4; ++j)
                    x[j] = cmul(v1[(b3 << 1) | (j >> 1)], v2[((j & 1) << 1) | b0]);
                #pragma unroll
                for (int j = 0; j < 4; ++j) {
                    float2 acc = make_float2(0.f, 0.f);
                    #pragma unroll
                    for (int k = 0; k < 4; ++k) {
                        float2 m = cmul(W[j*4+k], x[k]);
                        acc.x += m.x; acc.y += m.y;
                    }
                    y[j] = acc;
                }
                #pragma unroll
                for (int j = 0; j < 4; ++j) {
                    float p = y[j].x * y[j].x + y[j].y * y[j].y;
                    za += (j & 2) ? -p : p;    // bit2 = qubit a
                    zb += (j & 1) ? -p : p;    // bit1 = qubit a+1
                }
            }
        out[b * WIRES + a]     = za;
        out[b * WIRES + a + 1] = zb;
    } else if (seg == 6) {
        float2 v[4];
        ryblk(G + 0 * 16, inp[0], inp[1], v);   // block 0 on (0,1)
        float p0 = v[0].x*v[0].x + v[0].y*v[0].y;
        float p1 = v[1].x*v[1].x + v[1].y*v[1].y;
        float p2 = v[2].x*v[2].x + v[2].y*v[2].y;
        float p3 = v[3].x*v[3].x + v[3].y*v[3].y;
        out[b * WIRES + 0] = (p0 + p1) - (p2 + p3);   // bit1 = qubit 0
    } else {
        float2 v[4];
        ryblk(G + 6 * 16, inp[12], inp[13], v); // block 6 on (12,13)
        float p0 = v[0].x*v[0].x + v[0].y*v[0].y;
        float p1 = v[1].x*v[1].x + v[1].y*v[1].y;
        float p2 = v[2].x*v[2].x + v[2].y*v[2].y;
        float p3 = v[3].x*v[3].x + v[3].y*v[3].y;
        out[b * WIRES + 13] = (p0 - p1) + (p2 - p3);  // bit0 = qubit 13
    }
}

extern "C" void kernel_launch(void* const* d_in, const int* in_sizes, int n_in,
                              void* d_out, int out_size, void* d_ws, size_t ws_size,
                              hipStream_t stream) {
    const float* inputs = (const float*)d_in[0];
    const float* params = (const float*)d_in[1];
    float* out = (float*)d_out;
    float2* G = (float2*)d_ws;          // 13*16*8 = 1664 B scratch

    const int batch = in_sizes[0] / WIRES;
    gate_prep<<<1, 64, 0, stream>>>(params, G);
    dim3 grid((batch + 255) / 256, 8);
    lightcone<<<grid, 256, 0, stream>>>(inputs, G, out, batch);
}

// Round 11
// 14.853 us; speedup vs baseline: 11.2723x; 1.0473x over previous
//
#include <hip/hip_runtime.h>

#define WIRES 14
#define NVB 13                // variational blocks

__device__ __forceinline__ float2 cmul(float2 a, float2 b) {
    return make_float2(a.x * b.x - a.y * b.y, a.x * b.y + a.y * b.x);
}

// Fuse one 10-gate variational block k into a single complex 4x4 (local basis:
// b1 = q1 = first qubit of the pair). Verbatim math from the verified pipeline.
__device__ void fuse_block(const float* __restrict__ p, float2* __restrict__ Gk) {
    float2 U1[4], U2[4], U3[4], U4[4];
    auto rzrx = [](float trx, float trz, float2* U) {
        float cx, sx, cz, sz;
        sincosf(trx * 0.5f, &sx, &cx);
        sincosf(trz * 0.5f, &sz, &cz);
        float2 e0 = make_float2(cz, -sz);   // e^{-i h}
        float2 e1 = make_float2(cz,  sz);   // e^{+i h}
        U[0] = cmul(e0, make_float2(cx, 0.f));
        U[1] = cmul(e0, make_float2(0.f, -sx));
        U[2] = cmul(e1, make_float2(0.f, -sx));
        U[3] = cmul(e1, make_float2(cx, 0.f));
    };
    rzrx(p[0], p[1], U1);   // q1, first
    rzrx(p[2], p[3], U2);   // q2, first
    rzrx(p[5], p[6], U3);   // q1, second
    rzrx(p[7], p[8], U4);   // q2, second

    float2 K12[16], K34[16];
    #pragma unroll
    for (int r1 = 0; r1 < 2; ++r1)
        #pragma unroll
        for (int r2 = 0; r2 < 2; ++r2)
            #pragma unroll
            for (int c1 = 0; c1 < 2; ++c1)
                #pragma unroll
                for (int c2 = 0; c2 < 2; ++c2) {
                    int idx = (r1 * 2 + r2) * 4 + (c1 * 2 + c2);
                    K12[idx] = cmul(U1[r1 * 2 + c1], U2[r2 * 2 + c2]);
                    K34[idx] = cmul(U3[r1 * 2 + c1], U4[r2 * 2 + c2]);
                }

    float2 C1[16], C2[16];
    #pragma unroll
    for (int i = 0; i < 16; ++i) { C1[i] = make_float2(0.f, 0.f); C2[i] = make_float2(0.f, 0.f); }
    {
        float c, s;
        sincosf(p[4] * 0.5f, &s, &c);        // CRY ctrl=q1(high local bit), tgt=q2
        C1[0]  = make_float2(1.f, 0.f); C1[5]  = make_float2(1.f, 0.f);
        C1[10] = make_float2(c, 0.f);   C1[11] = make_float2(-s, 0.f);
        C1[14] = make_float2(s, 0.f);   C1[15] = make_float2(c, 0.f);
        sincosf(p[9] * 0.5f, &s, &c);        // CRY ctrl=q2(low local bit), tgt=q1
        C2[0]  = make_float2(1.f, 0.f); C2[10] = make_float2(1.f, 0.f);
        C2[5]  = make_float2(c, 0.f);   C2[7]  = make_float2(-s, 0.f);
        C2[13] = make_float2(s, 0.f);   C2[15] = make_float2(c, 0.f);
    }

    float2 T1[16], T2[16];
    #pragma unroll
    for (int r = 0; r < 4; ++r)
        #pragma unroll
        for (int c = 0; c < 4; ++c) {
            float2 a = make_float2(0.f, 0.f);
            #pragma unroll
            for (int j = 0; j < 4; ++j) { float2 m = cmul(C1[r*4+j], K12[j*4+c]); a.x += m.x; a.y += m.y; }
            T1[r*4+c] = a;
        }
    #pragma unroll
    for (int r = 0; r < 4; ++r)
        #pragma unroll
        for (int c = 0; c < 4; ++c) {
            float2 a = make_float2(0.f, 0.f);
            #pragma unroll
            for (int j = 0; j < 4; ++j) { float2 m = cmul(K34[r*4+j], T1[j*4+c]); a.x += m.x; a.y += m.y; }
            T2[r*4+c] = a;
        }
    #pragma unroll
    for (int r = 0; r < 4; ++r)
        #pragma unroll
        for (int c = 0; c < 4; ++c) {
            float2 a = make_float2(0.f, 0.f);
            #pragma unroll
            for (int j = 0; j < 4; ++j) { float2 m = cmul(C2[r*4+j], T2[j*4+c]); a.x += m.x; a.y += m.y; }
            Gk[r*4+c] = a;
        }
}

// ============ single fused kernel: per-block gate fusion + light-cone eval ============
// Depth-2 brick wall => <Z_q> depends on at most 4 qubits:
//   q in layer-2 pair (a,a+1), a=2*seg+1: cone = {a-1,a,a+1,a+2};
//   blocks: L1 G[seg] on (a-1,a), L1 G[seg+1] on (a+1,a+2), L2 G[7+seg] on (a,a+1).
//   seg 6 -> Z_0 via G[0] only; seg 7 -> Z_13 via G[6] only.
// Each block fuses only the <=3 matrices it needs (lanes 0..2), then evaluates
// 256 samples. One kernel launch total.
__global__ __launch_bounds__(256)
void lightcone_fused(const float* __restrict__ inputs, const float* __restrict__ params,
                     float* __restrict__ out, int batch) {
    __shared__ float2 Gs[3 * 16];      // [0]=L1 left, [1]=L1 right, [2]=L2
    const int seg = blockIdx.y;
    const int t = threadIdx.x;

    if (seg < 6) {
        if (t < 3) {
            const int k = (t == 0) ? seg : (t == 1) ? (seg + 1) : (7 + seg);
            fuse_block(params + k * 10, Gs + t * 16);
        }
    } else {
        if (t == 0) fuse_block(params + (seg == 6 ? 0 : 6) * 10, Gs);
    }
    __syncthreads();

    const int b = blockIdx.x * 256 + t;
    if (b >= batch) return;
    const float* inp = inputs + b * WIRES;

    // v = B * (RY(tp) (x) RY(tq)) |00>  — B complex 4x4, product state real
    auto ryblk = [](const float2* __restrict__ B, float tp, float tq, float2 v[4]) {
        float cp, sp, cq, sq;
        sincosf(tp * 0.5f, &sp, &cp);
        sincosf(tq * 0.5f, &sq, &cq);
        const float e0 = cp * cq, e1 = cp * sq, e2 = sp * cq, e3 = sp * sq;
        #pragma unroll
        for (int j = 0; j < 4; ++j) {
            v[j].x = B[j*4+0].x*e0 + B[j*4+1].x*e1 + B[j*4+2].x*e2 + B[j*4+3].x*e3;
            v[j].y = B[j*4+0].y*e0 + B[j*4+1].y*e1 + B[j*4+2].y*e2 + B[j*4+3].y*e3;
        }
    };

    if (seg < 6) {
        const int a = 2 * seg + 1;
        float2 v1[4], v2[4];
        ryblk(Gs + 0 * 16, inp[a - 1], inp[a],     v1);   // (a-1, a)
        ryblk(Gs + 1 * 16, inp[a + 1], inp[a + 2], v2);   // (a+1, a+2)
        const float2* W = Gs + 2 * 16;                    // L2 on (a, a+1)

        float za = 0.f, zb = 0.f;
        #pragma unroll
        for (int b3 = 0; b3 < 2; ++b3)
            #pragma unroll
            for (int b0 = 0; b0 < 2; ++b0) {
                // x[j], j=(b2<<1)|b1 : psi = v1[(b3<<1)|b2] * v2[(b1<<1)|b0]
                float2 x[4], y[4];
                #pragma unroll
                for (int j = 0; j < 4; ++j)
                    x[j] = cmul(v1[(b3 << 1) | (j >> 1)], v2[((j & 1) << 1) | b0]);
                #pragma unroll
                for (int j = 0; j < 4; ++j) {
                    float2 acc = make_float2(0.f, 0.f);
                    #pragma unroll
                    for (int k = 0; k < 4; ++k) {
                        float2 m = cmul(W[j*4+k], x[k]);
                        acc.x += m.x; acc.y += m.y;
                    }
                    y[j] = acc;
                }
                #pragma unroll
                for (int j = 0; j < 4; ++j) {
                    float p = y[j].x * y[j].x + y[j].y * y[j].y;
                    za += (j & 2) ? -p : p;    // bit2 = qubit a
                    zb += (j & 1) ? -p : p;    // bit1 = qubit a+1
                }
            }
        out[b * WIRES + a]     = za;
        out[b * WIRES + a + 1] = zb;
    } else if (seg == 6) {
        float2 v[4];
        ryblk(Gs, inp[0], inp[1], v);           // block 0 on (0,1)
        float p0 = v[0].x*v[0].x + v[0].y*v[0].y;
        float p1 = v[1].x*v[1].x + v[1].y*v[1].y;
        float p2 = v[2].x*v[2].x + v[2].y*v[2].y;
        float p3 = v[3].x*v[3].x + v[3].y*v[3].y;
        out[b * WIRES + 0] = (p0 + p1) - (p2 + p3);   // bit1 = qubit 0
    } else {
        float2 v[4];
        ryblk(Gs, inp[12], inp[13], v);         // block 6 on (12,13)
        float p0 = v[0].x*v[0].x + v[0].y*v[0].y;
        float p1 = v[1].x*v[1].x + v[1].y*v[1].y;
        float p2 = v[2].x*v[2].x + v[2].y*v[2].y;
        float p3 = v[3].x*v[3].x + v[3].y*v[3].y;
        out[b * WIRES + 13] = (p0 - p1) + (p2 - p3);  // bit0 = qubit 13
    }
}

extern "C" void kernel_launch(void* const* d_in, const int* in_sizes, int n_in,
                              void* d_out, int out_size, void* d_ws, size_t ws_size,
                              hipStream_t stream) {
    const float* inputs = (const float*)d_in[0];
    const float* params = (const float*)d_in[1];
    float* out = (float*)d_out;

    const int batch = in_sizes[0] / WIRES;
    dim3 grid((batch + 255) / 256, 8);
    lightcone_fused<<<grid, 256, 0, stream>>>(inputs, params, out, batch);
}